// Round 8
// baseline (308.348 us; speedup 1.0000x reference)
//
#include <hip/hip_runtime.h>

typedef __attribute__((ext_vector_type(4))) float f32x4;
typedef __attribute__((ext_vector_type(16))) float f32x16;
typedef __attribute__((ext_vector_type(8))) short bf16x8;
typedef unsigned short u16;
typedef unsigned int u32;

constexpr int NN     = 4096;   // H*W
constexpr int SPLITS = 8;      // m-splits
constexpr int TPB    = 8;      // 64 / SPLITS tiles per split
constexpr int NBLK   = 512;    // grid size (2 blocks/CU, all co-resident)

__device__ __forceinline__ u16 f2bf(float f){
  u32 u = __builtin_bit_cast(u32, f);
  u += 0x7FFFu + ((u >> 16) & 1u);          // round-to-nearest-even
  return (u16)(u >> 16);
}
__device__ __forceinline__ u32 cvtpk(float lo, float hi){
  u32 r;
  asm("v_cvt_pk_bf16_f32 %0, %1, %2" : "=v"(r) : "v"(lo), "v"(hi));
  return r;
}
__device__ __forceinline__ float fexp2(float x){
  float r;
  asm("v_exp_f32 %0, %1" : "=v"(r) : "v"(x));
  return r;
}
__device__ __forceinline__ void async16(void* lds, const void* g){
  __builtin_amdgcn_global_load_lds((const __attribute__((address_space(1))) void*)g,
                                   (__attribute__((address_space(3))) void*)lds,
                                   16, 0, 0);
}

union SMem {
  struct { float W[3 * 4096]; float B[192]; } a;       // proj: 48.75 KB
  struct { u16 phi[2][4096]; u16 g[2][4096]; } b;      // attn: 32 KB
  struct { u16 y[4096]; float inv[64]; } c;            // combine: 8.25 KB
};

// Grid-wide barrier: all NBLK blocks co-resident by capacity construction.
// Device-scope atomics + __threadfence for cross-XCD visibility (G16).
__device__ __forceinline__ void grid_barrier(u32* cnt, u32* flag){
  __threadfence();                 // flush this thread's writes (all threads)
  __syncthreads();
  if (threadIdx.x == 0){
    if (atomicAdd(cnt, 1u) == (u32)(NBLK - 1)){
      atomicExch(flag, 1u);
    } else {
      while (atomicOr(flag, 0u) == 0u) __builtin_amdgcn_s_sleep(16);
    }
    __threadfence();               // invalidate stale cache before reads
  }
  __syncthreads();
}

__global__ void barrier_init(u32* bar){
  if (threadIdx.x < 4) bar[threadIdx.x] = 0u;
}

// ---------------------------------------------------------------------------
// mega: proj -> gridbar -> attn (32x32 MFMA flash, S=8) -> gridbar -> combine
// ---------------------------------------------------------------------------
__global__ __launch_bounds__(512, 4) void mega_kernel(
    const float* __restrict__ x,
    const float* __restrict__ wth, const float* __restrict__ bth,
    const float* __restrict__ wph, const float* __restrict__ bph,
    const float* __restrict__ wg,  const float* __restrict__ bg,
    const float* __restrict__ w_out, const float* __restrict__ b_out,
    const float* __restrict__ bn_gamma, const float* __restrict__ bn_beta,
    float* __restrict__ out,
    u16* __restrict__ theta_t, u16* __restrict__ phi_t, u16* __restrict__ gbuf,
    u16* __restrict__ y_part, float* __restrict__ l_part, u32* bar)
{
  __shared__ SMem sm;
  const int bid = blockIdx.x;
  const int t   = threadIdx.x;
  const int w   = __builtin_amdgcn_readfirstlane(t >> 6);  // wave 0..7
  const int l   = t & 63;

  // ======================= Phase A: proj (blocks 0..255) ====================
  if (bid < 256){
#pragma unroll
    for (int i = 0; i < 6; ++i){
      const int idx = i * 512 + t;           // 0..3071 float4s
      const float4 v = (idx < 1024) ? ((const float4*)wth)[idx]
                     : (idx < 2048) ? ((const float4*)wph)[idx - 1024]
                                    : ((const float4*)wg)[idx - 2048];
      ((float4*)sm.a.W)[idx] = v;
    }
    if (t < 192) sm.a.B[t] = (t < 64) ? bth[t] : (t < 128) ? bph[t - 64] : bg[t - 128];

    const int b = bid >> 6;
    const int n = (bid & 63) * 64 + l;
    const float* xb = x + ((size_t)b * 64) * NN + n;
    float xr[64];
#pragma unroll
    for (int c = 0; c < 64; ++c) xr[c] = xb[(size_t)c * NN];
    __syncthreads();

    for (int mat = 0; mat < 3; ++mat){
      const float* Wm = sm.a.W + mat * 4096 + (w * 8) * 64;
      float acc[8];
#pragma unroll
      for (int oo = 0; oo < 8; ++oo) acc[oo] = sm.a.B[mat * 64 + w * 8 + oo];
#pragma unroll
      for (int c4 = 0; c4 < 16; ++c4)
#pragma unroll
        for (int oo = 0; oo < 8; ++oo){
          const float4 wv = *(const float4*)&Wm[oo * 64 + c4 * 4];  // wave-broadcast
          acc[oo] = fmaf(wv.x, xr[4 * c4],     acc[oo]);
          acc[oo] = fmaf(wv.y, xr[4 * c4 + 1], acc[oo]);
          acc[oo] = fmaf(wv.z, xr[4 * c4 + 2], acc[oo]);
          acc[oo] = fmaf(wv.w, xr[4 * c4 + 3], acc[oo]);
        }
      if (mat == 0){
#pragma unroll
        for (int oo = 0; oo < 8; ++oo) acc[oo] *= 1.44269504088896340736f;
      }
      if (mat < 2){
        uint4 pk;
        pk.x = cvtpk(acc[0], acc[1]); pk.y = cvtpk(acc[2], acc[3]);
        pk.z = cvtpk(acc[4], acc[5]); pk.w = cvtpk(acc[6], acc[7]);
        u16* base = (mat == 0) ? theta_t : phi_t;
        *(uint4*)(base + ((size_t)(b * NN + n)) * 64 + w * 8) = pk;
      } else {
#pragma unroll
        for (int oo = 0; oo < 8; ++oo)
          gbuf[((size_t)(b * 64 + w * 8 + oo)) * NN + n] = f2bf(acc[oo]);
      }
    }
  }
  grid_barrier(bar, bar + 1);

  // ======================= Phase B: attn (all 512 blocks) ===================
  {
    const int cpx = NBLK >> 3;
    const int lb  = (bid & 7) * cpx + (bid >> 3);   // bijective XCD swizzle

    const int ms  = lb >> 6;            // m-split 0..7
    const int pr  = lb & 63;
    const int b   = pr >> 4;
    const int n0  = (pr & 15) * 256;

    const int cc  = l & 31;
    const int h   = l >> 5;
    const int sw  = (cc & 7) << 4;
    const int rb  = cc * 128;

    const u16* thb = theta_t + (size_t)b * NN * 64;

    bf16x8 tf[4];
#pragma unroll
    for (int ks = 0; ks < 4; ++ks)
      tf[ks] = *(const bf16x8*)(thb + (size_t)(n0 + w * 32 + cc) * 64 + ks * 16 + h * 8);

    const int m0 = ms * TPB;
    const int r8 = l >> 3;
    const int c8 = l & 7;
    const u16* phi_src = phi_t + (size_t)b * NN * 64
                       + (size_t)(m0 * 64 + w * 8 + r8) * 64 + (c8 ^ r8) * 8;
    const u16* g_src   = gbuf + (size_t)b * 64 * NN
                       + (size_t)(w * 8 + r8) * NN + m0 * 64 + (c8 ^ r8) * 8;

    f32x16 yacc0, yacc1;
#pragma unroll
    for (int i = 0; i < 16; ++i){ yacc0[i] = 0.f; yacc1[i] = 0.f; }
    float lacc = 0.f;

    async16(&sm.b.phi[0][w * 512], phi_src);
    async16(&sm.b.g[0][w * 512],   g_src);
    phi_src += 4096; g_src += 64;

#pragma unroll 2
    for (int it = 0; it < TPB; ++it){
      const int cur = it & 1;
      if (it < TPB - 1){
        async16(&sm.b.phi[cur ^ 1][w * 512], phi_src);
        async16(&sm.b.g[cur ^ 1][w * 512],   g_src);
        phi_src += 4096; g_src += 64;
        asm volatile("s_waitcnt vmcnt(2)" ::: "memory");
      } else {
        asm volatile("s_waitcnt vmcnt(0)" ::: "memory");
      }
      __builtin_amdgcn_s_barrier();

      const char* phiB = (const char*)&sm.b.phi[cur][0];
      const char* gB   = (const char*)&sm.b.g[cur][0];

#pragma unroll
      for (int tt = 0; tt < 2; ++tt){
        __builtin_amdgcn_s_setprio(1);
        f32x16 p;
#pragma unroll
        for (int i = 0; i < 16; ++i) p[i] = 0.f;
#pragma unroll
        for (int ks = 0; ks < 4; ++ks)
          p = __builtin_amdgcn_mfma_f32_32x32x16_bf16(
                *(const bf16x8*)(phiB + tt * 4096 + rb + ((ks * 32 + h * 16) ^ sw)),
                tf[ks], p, 0, 0, 0);
        __builtin_amdgcn_s_setprio(0);

        u32 wpk[4][2];
#pragma unroll
        for (int rq = 0; rq < 4; ++rq){
          const float e0 = fexp2(p[4 * rq + 0]), e1 = fexp2(p[4 * rq + 1]);
          const float e2 = fexp2(p[4 * rq + 2]), e3 = fexp2(p[4 * rq + 3]);
          lacc += (e0 + e1) + (e2 + e3);
          wpk[rq][0] = cvtpk(e0, e1);
          wpk[rq][1] = cvtpk(e2, e3);
        }

        __builtin_amdgcn_s_setprio(1);
#pragma unroll
        for (int par = 0; par < 2; ++par){
          u32 A0 = wpk[2 * par][0],     A1 = wpk[2 * par][1];
          u32 B0 = wpk[2 * par + 1][0], B1 = wpk[2 * par + 1][1];
          asm("v_permlane32_swap_b32 %0, %1" : "+v"(A0), "+v"(B0));
          asm("v_permlane32_swap_b32 %0, %1" : "+v"(A1), "+v"(B1));
          union { u32 u[4]; bf16x8 v; } pw;
          pw.u[0] = A0; pw.u[1] = A1; pw.u[2] = B0; pw.u[3] = B1;
          const int s   = tt * 2 + par;
          const int gof = (s * 32 + h * 16) ^ sw;
          yacc0 = __builtin_amdgcn_mfma_f32_32x32x16_bf16(
                    pw.v, *(const bf16x8*)(gB + rb + gof), yacc0, 0, 0, 0);
          yacc1 = __builtin_amdgcn_mfma_f32_32x32x16_bf16(
                    pw.v, *(const bf16x8*)(gB + 4096 + rb + gof), yacc1, 0, 0, 0);
        }
        __builtin_amdgcn_s_setprio(0);
      }
      __builtin_amdgcn_s_barrier();
    }

    // cross-half l combine
    {
      u32 la = __builtin_bit_cast(u32, lacc), lb2 = la;
      asm("v_permlane32_swap_b32 %0, %1" : "+v"(la), "+v"(lb2));
      const float ltot = __builtin_bit_cast(float, la) + __builtin_bit_cast(float, lb2);
      if (l < 32)
        l_part[(size_t)(ms * 4 + b) * NN + n0 + w * 32 + cc] = ltot;
    }

    u16* yp = y_part + ((size_t)(ms * 4 + b) * NN + n0 + w * 32) * 64 + cc;
#pragma unroll
    for (int r = 0; r < 16; ++r){
      const int nl = (r & 3) + 8 * (r >> 2) + 4 * h;
      yp[(size_t)nl * 64]      = f2bf(yacc0[r]);
      yp[(size_t)nl * 64 + 32] = f2bf(yacc1[r]);
    }
  }
  grid_barrier(bar + 2, bar + 3);

  // ======================= Phase C: combine (blocks 0..255) =================
  if (bid < 256){
    const int b     = bid >> 6;
    const int nbase = (bid & 63) * 64;
    const int row   = t >> 3;            // 0..63
    const int ch    = t & 7;

    float s[8] = {0.f,0.f,0.f,0.f,0.f,0.f,0.f,0.f};
#pragma unroll
    for (int ms = 0; ms < SPLITS; ++ms){
      const uint4 v = *(const uint4*)(y_part
                    + ((size_t)(ms * 4 + b) * NN + nbase + row) * 64 + ch * 8);
      const u32 ww[4] = {v.x, v.y, v.z, v.w};
#pragma unroll
      for (int i = 0; i < 4; ++i){
        s[2 * i]     += __builtin_bit_cast(float, ww[i] << 16);
        s[2 * i + 1] += __builtin_bit_cast(float, ww[i] & 0xFFFF0000u);
      }
    }
    if (t < 64){
      float ls = 0.f;
#pragma unroll
      for (int ms = 0; ms < SPLITS; ++ms)
        ls += l_part[(size_t)(ms * 4 + b) * NN + nbase + t];
      sm.c.inv[t] = 1.0f / ls;
    }
    __syncthreads();

    {
      const float inv = sm.c.inv[row];
      uint4 pk;
      pk.x = cvtpk(s[0] * inv, s[1] * inv);
      pk.y = cvtpk(s[2] * inv, s[3] * inv);
      pk.z = cvtpk(s[4] * inv, s[5] * inv);
      pk.w = cvtpk(s[6] * inv, s[7] * inv);
      *(uint4*)((char*)sm.c.y + ((row * 128 + ch * 16) ^ ((row & 7) << 4))) = pk;
    }
    __syncthreads();

    const int q   = l & 15;
    const int gg  = l >> 4;
    const int cq  = w & 3;              // c-group (16 channels)
    const int nh  = w >> 2;             // n-half (32 of 64 rows)
    const int swz = (q & 7) << 4;

    bf16x8 wf[2];
#pragma unroll
    for (int ks = 0; ks < 2; ++ks){
      bf16x8 v;
#pragma unroll
      for (int jj = 0; jj < 8; ++jj)
        v[jj] = (short)f2bf(w_out[(cq * 16 + q) * 64 + ks * 32 + gg * 8 + jj]);
      wf[ks] = v;
    }
    f32x4 zacc[2];
    zacc[0] = (f32x4){0.f, 0.f, 0.f, 0.f};
    zacc[1] = (f32x4){0.f, 0.f, 0.f, 0.f};
#pragma unroll
    for (int ks = 0; ks < 2; ++ks)
#pragma unroll
      for (int ns = 0; ns < 2; ++ns){
        const int row2 = nh * 32 + ns * 16 + q;
        const int off  = ((row2 * 128) + ks * 64 + gg * 16) ^ swz;
        const bf16x8 yf = *(const bf16x8*)((const char*)sm.c.y + off);
        zacc[ns] = __builtin_amdgcn_mfma_f32_16x16x32_bf16(wf[ks], yf, zacc[ns], 0, 0, 0);
      }

    float bo[4], sc_[4], bb_[4];
#pragma unroll
    for (int r = 0; r < 4; ++r){
      const int c = cq * 16 + gg * 4 + r;
      bo[r]  = b_out[c];
      sc_[r] = bn_gamma[c] * 0.99999500003749969f;  // 1/sqrt(1+1e-5)
      bb_[r] = bn_beta[c];
    }
#pragma unroll
    for (int ns = 0; ns < 2; ++ns)
#pragma unroll
      for (int r = 0; r < 4; ++r){
        const int c  = cq * 16 + gg * 4 + r;
        const int ng = nbase + nh * 32 + ns * 16 + q;
        const size_t idx = ((size_t)(b * 64 + c)) * NN + ng;
        float z = zacc[ns][r] + bo[r];
        z = fmaxf(z, 0.0f);
        z = z * sc_[r] + bb_[r];
        out[idx] = x[idx] + z;
      }
  }
}

// ---------------------------------------------------------------------------
extern "C" void kernel_launch(void* const* d_in, const int* in_sizes, int n_in,
                              void* d_out, int out_size, void* d_ws, size_t ws_size,
                              hipStream_t stream)
{
  (void)in_sizes; (void)n_in; (void)out_size; (void)ws_size;
  const float* x        = (const float*)d_in[0];
  const float* w_theta  = (const float*)d_in[1];
  const float* b_theta  = (const float*)d_in[2];
  const float* w_phi    = (const float*)d_in[3];
  const float* b_phi    = (const float*)d_in[4];
  const float* w_g      = (const float*)d_in[5];
  const float* b_g      = (const float*)d_in[6];
  const float* w_out    = (const float*)d_in[7];
  const float* b_out    = (const float*)d_in[8];
  const float* bn_gamma = (const float*)d_in[9];
  const float* bn_beta  = (const float*)d_in[10];
  float* out = (float*)d_out;

  u16* theta_t = (u16*)d_ws;                           // 2 MB
  u16* phi_t   = theta_t + (size_t)4 * NN * 64;        // 2 MB
  u16* gbuf    = phi_t   + (size_t)4 * NN * 64;        // 2 MB
  u16* y_part  = gbuf    + (size_t)4 * NN * 64;        // 16.8 MB (S=8 bf16)
  float* l_part = (float*)(y_part + (size_t)SPLITS * 4 * NN * 64);  // 512 KB
  u32* bar      = (u32*)(l_part + (size_t)SPLITS * 4 * NN);

  barrier_init<<<1, 64, 0, stream>>>(bar);
  mega_kernel<<<NBLK, 512, 0, stream>>>(
      x, w_theta, b_theta, w_phi, b_phi, w_g, b_g,
      w_out, b_out, bn_gamma, bn_beta, out,
      theta_t, phi_t, gbuf, y_part, l_part, bar);
}

// Round 9
// 49.817 us; speedup vs baseline: 6.1897x; 6.1897x over previous
//
#include <hip/hip_runtime.h>

typedef __attribute__((ext_vector_type(4))) float f32x4;
typedef __attribute__((ext_vector_type(16))) float f32x16;
typedef __attribute__((ext_vector_type(8))) short bf16x8;
typedef unsigned short u16;
typedef unsigned int u32;

constexpr int NN = 4096;   // H*W

__device__ __forceinline__ u16 f2bf(float f){
  u32 u = __builtin_bit_cast(u32, f);
  u += 0x7FFFu + ((u >> 16) & 1u);          // round-to-nearest-even
  return (u16)(u >> 16);
}
__device__ __forceinline__ u32 cvtpk(float lo, float hi){
  u32 r;
  asm("v_cvt_pk_bf16_f32 %0, %1, %2" : "=v"(r) : "v"(lo), "v"(hi));
  return r;
}
__device__ __forceinline__ float fexp2(float x){
  float r;
  asm("v_exp_f32 %0, %1" : "=v"(r) : "v"(x));
  return r;
}
__device__ __forceinline__ void async16(void* lds, const void* g){
  __builtin_amdgcn_global_load_lds((const __attribute__((address_space(1))) void*)g,
                                   (__attribute__((address_space(3))) void*)lds,
                                   16, 0, 0);
}

// ---------------------------------------------------------------------------
// proj v7: 512 blocks (2/CU -> 2 waves/SIMD TLP). Block = (batch, n-chunk 64,
// o-half 32). 4 waves x 8 outputs. Weights LDS-staged (48 KB).
// theta gets *log2e folded in. theta_t/phi_t: [b][n][o] bf16; g: [b][o][n].
// ---------------------------------------------------------------------------
__global__ __launch_bounds__(256) void proj_kernel(
    const float* __restrict__ x,
    const float* __restrict__ wth, const float* __restrict__ bth,
    const float* __restrict__ wph, const float* __restrict__ bph,
    const float* __restrict__ wg,  const float* __restrict__ bg,
    u16* __restrict__ theta_t, u16* __restrict__ phi_t, u16* __restrict__ gbuf)
{
  __shared__ float Wsm[3 * 4096];   // 48 KB
  __shared__ float Bsm[3 * 64];

  const int t = threadIdx.x;
#pragma unroll
  for (int i = 0; i < 4; ++i){
    ((float4*)Wsm)[i * 256 + t]            = ((const float4*)wth)[i * 256 + t];
    ((float4*)(Wsm + 4096))[i * 256 + t]   = ((const float4*)wph)[i * 256 + t];
    ((float4*)(Wsm + 8192))[i * 256 + t]   = ((const float4*)wg)[i * 256 + t];
  }
  if (t < 64){ Bsm[t] = bth[t]; Bsm[64 + t] = bph[t]; Bsm[128 + t] = bg[t]; }

  const int bid  = blockIdx.x;
  const int b    = bid >> 7;
  const int half = (bid >> 6) & 1;           // o-half
  const int n    = (bid & 63) * 64 + (t & 63);
  const int w    = __builtin_amdgcn_readfirstlane(t >> 6);
  const int ob   = half * 32 + w * 8;        // this wave's 8-output base

  const float* xb = x + ((size_t)b * 64) * NN + n;
  float xr[64];
#pragma unroll
  for (int c = 0; c < 64; ++c) xr[c] = xb[(size_t)c * NN];

  __syncthreads();

  for (int mat = 0; mat < 3; ++mat){
    const float* Wm = Wsm + mat * 4096 + ob * 64;
    float acc[8];
#pragma unroll
    for (int oo = 0; oo < 8; ++oo) acc[oo] = Bsm[mat * 64 + ob + oo];
#pragma unroll
    for (int c4 = 0; c4 < 16; ++c4)
#pragma unroll
      for (int oo = 0; oo < 8; ++oo){
        const float4 wv = *(const float4*)&Wm[oo * 64 + c4 * 4];  // wave-broadcast
        acc[oo] = fmaf(wv.x, xr[4 * c4],     acc[oo]);
        acc[oo] = fmaf(wv.y, xr[4 * c4 + 1], acc[oo]);
        acc[oo] = fmaf(wv.z, xr[4 * c4 + 2], acc[oo]);
        acc[oo] = fmaf(wv.w, xr[4 * c4 + 3], acc[oo]);
      }
    if (mat == 0){
#pragma unroll
      for (int oo = 0; oo < 8; ++oo) acc[oo] *= 1.44269504088896340736f;
    }
    if (mat < 2){
      uint4 pk;
      pk.x = cvtpk(acc[0], acc[1]); pk.y = cvtpk(acc[2], acc[3]);
      pk.z = cvtpk(acc[4], acc[5]); pk.w = cvtpk(acc[6], acc[7]);
      u16* base = (mat == 0) ? theta_t : phi_t;
      *(uint4*)(base + ((size_t)(b * NN + n)) * 64 + ob) = pk;
    } else {
#pragma unroll
      for (int oo = 0; oo < 8; ++oo)
        gbuf[((size_t)(b * 64 + ob + oo)) * NN + n] = f2bf(acc[oo]);
    }
  }
}

// ---------------------------------------------------------------------------
// attn v8: 32x32x16 MFMA flash, single-barrier-per-tile schedule
// {vmcnt(0); barrier; STAGE(t+1); compute(t)}. BM=256 (8 waves x 32 rows),
// m-split S, XCD-aware bijective swizzle. grid = 64*S x 512 threads.
// ---------------------------------------------------------------------------
template<int TPB>
__global__ __launch_bounds__(512, 4) void attn_kernel(
    const u16* __restrict__ theta_t, const u16* __restrict__ phi_t,
    const u16* __restrict__ gbuf,
    u16* __restrict__ y_part, float* __restrict__ l_part)
{
  __shared__ u16 phi_sm[2][64 * 64];  // [m_loc][o], XOR-swizzled
  __shared__ u16 g_sm[2][64 * 64];    // [o][m_loc], XOR-swizzled

  const int j   = blockIdx.x;
  const int cpx = gridDim.x >> 3;
  const int lb  = (j & 7) * cpx + (j >> 3);   // bijective (grid % 8 == 0)

  const int ms  = lb >> 6;            // m-split index
  const int pr  = lb & 63;
  const int b   = pr >> 4;
  const int n0  = (pr & 15) * 256;

  const int tid = threadIdx.x;
  const int w   = __builtin_amdgcn_readfirstlane(tid >> 6); // 0..7
  const int l   = tid & 63;
  const int cc  = l & 31;
  const int h   = l >> 5;
  const int sw  = (cc & 7) << 4;
  const int rb  = cc * 128;

  const u16* thb = theta_t + (size_t)b * NN * 64;

  bf16x8 tf[4];
#pragma unroll
  for (int ks = 0; ks < 4; ++ks)
    tf[ks] = *(const bf16x8*)(thb + (size_t)(n0 + w * 32 + cc) * 64 + ks * 16 + h * 8);

  const int m0 = ms * TPB;
  const int r8 = l >> 3;
  const int c8 = l & 7;
  const u16* phi_src = phi_t + (size_t)b * NN * 64
                     + (size_t)(m0 * 64 + w * 8 + r8) * 64 + (c8 ^ r8) * 8;
  const u16* g_src   = gbuf + (size_t)b * 64 * NN
                     + (size_t)(w * 8 + r8) * NN + m0 * 64 + (c8 ^ r8) * 8;

  f32x16 yacc0, yacc1;
#pragma unroll
  for (int i = 0; i < 16; ++i){ yacc0[i] = 0.f; yacc1[i] = 0.f; }
  float lacc = 0.f;

  // prologue: stage tile 0
  async16(&phi_sm[0][w * 512], phi_src);
  async16(&g_sm[0][w * 512],   g_src);
  phi_src += 4096; g_src += 64;

#pragma unroll 2
  for (int it = 0; it < TPB; ++it){
    const int cur = it & 1;
    // own 2 in-flight loads for tile `it` must be in LDS before barrier
    asm volatile("s_waitcnt vmcnt(0)" ::: "memory");
    __builtin_amdgcn_s_barrier();
    if (it < TPB - 1){
      // stage t+1 into the buffer freed at this barrier; hides under compute
      async16(&phi_sm[cur ^ 1][w * 512], phi_src);
      async16(&g_sm[cur ^ 1][w * 512],   g_src);
      phi_src += 4096; g_src += 64;
    }

    const char* phiB = (const char*)&phi_sm[cur][0];
    const char* gB   = (const char*)&g_sm[cur][0];

#pragma unroll
    for (int tt = 0; tt < 2; ++tt){
      __builtin_amdgcn_s_setprio(1);
      f32x16 p;
#pragma unroll
      for (int i = 0; i < 16; ++i) p[i] = 0.f;
#pragma unroll
      for (int ks = 0; ks < 4; ++ks)
        p = __builtin_amdgcn_mfma_f32_32x32x16_bf16(
              *(const bf16x8*)(phiB + tt * 4096 + rb + ((ks * 32 + h * 16) ^ sw)),
              tf[ks], p, 0, 0, 0);
      __builtin_amdgcn_s_setprio(0);

      u32 wpk[4][2];
#pragma unroll
      for (int rq = 0; rq < 4; ++rq){
        const float e0 = fexp2(p[4 * rq + 0]), e1 = fexp2(p[4 * rq + 1]);
        const float e2 = fexp2(p[4 * rq + 2]), e3 = fexp2(p[4 * rq + 3]);
        lacc += (e0 + e1) + (e2 + e3);
        wpk[rq][0] = cvtpk(e0, e1);
        wpk[rq][1] = cvtpk(e2, e3);
      }

      __builtin_amdgcn_s_setprio(1);
#pragma unroll
      for (int par = 0; par < 2; ++par){
        u32 A0 = wpk[2 * par][0],     A1 = wpk[2 * par][1];
        u32 B0 = wpk[2 * par + 1][0], B1 = wpk[2 * par + 1][1];
        asm("v_permlane32_swap_b32 %0, %1" : "+v"(A0), "+v"(B0));
        asm("v_permlane32_swap_b32 %0, %1" : "+v"(A1), "+v"(B1));
        union { u32 u[4]; bf16x8 v; } pw;
        pw.u[0] = A0; pw.u[1] = A1; pw.u[2] = B0; pw.u[3] = B1;
        const int s   = tt * 2 + par;
        const int gof = (s * 32 + h * 16) ^ sw;
        yacc0 = __builtin_amdgcn_mfma_f32_32x32x16_bf16(
                  pw.v, *(const bf16x8*)(gB + rb + gof), yacc0, 0, 0, 0);
        yacc1 = __builtin_amdgcn_mfma_f32_32x32x16_bf16(
                  pw.v, *(const bf16x8*)(gB + 4096 + rb + gof), yacc1, 0, 0, 0);
      }
      __builtin_amdgcn_s_setprio(0);
    }
  }

  // cross-half l combine
  {
    u32 la = __builtin_bit_cast(u32, lacc), lb2 = la;
    asm("v_permlane32_swap_b32 %0, %1" : "+v"(la), "+v"(lb2));
    const float ltot = __builtin_bit_cast(float, la) + __builtin_bit_cast(float, lb2);
    if (l < 32)
      l_part[(size_t)(ms * 4 + b) * NN + n0 + w * 32 + cc] = ltot;
  }

  u16* yp = y_part + ((size_t)(ms * 4 + b) * NN + n0 + w * 32) * 64 + cc;
#pragma unroll
  for (int r = 0; r < 16; ++r){
    const int nl = (r & 3) + 8 * (r >> 2) + 4 * h;
    yp[(size_t)nl * 64]      = f2bf(yacc0[r]);
    yp[(size_t)nl * 64 + 32] = f2bf(yacc1[r]);
  }
}

// ---------------------------------------------------------------------------
// combine: 512 blocks x 32 rows. Sum S bf16 partials, normalize,
// w_out GEMM + bias/ReLU/BN + residual.
// ---------------------------------------------------------------------------
__global__ __launch_bounds__(256) void combine_kernel(
    const u16* __restrict__ y_part, const float* __restrict__ l_part,
    const float* __restrict__ x,
    const float* __restrict__ w_out, const float* __restrict__ b_out,
    const float* __restrict__ bn_gamma, const float* __restrict__ bn_beta,
    float* __restrict__ out, int S)
{
  __shared__ u16 y_sm[32 * 64];       // [row][o] bf16, swizzled
  __shared__ float inv_sm[32];

  const int cb   = blockIdx.x;            // 0..511
  const int b    = cb >> 7;
  const int nin  = (cb & 127) * 32;       // row base within batch
  const int t    = threadIdx.x;
  const int row  = t >> 3;                // 0..31
  const int ch   = t & 7;                 // 16B chunk (8 bf16)

  float s[8] = {0.f,0.f,0.f,0.f,0.f,0.f,0.f,0.f};
  for (int ms = 0; ms < S; ++ms){
    const u16* src = y_part + ((size_t)(ms * 4 + b) * NN + nin + row) * 64 + ch * 8;
    const uint4 v = *(const uint4*)src;
    const u32 ww[4] = {v.x, v.y, v.z, v.w};
#pragma unroll
    for (int i = 0; i < 4; ++i){
      s[2 * i]     += __builtin_bit_cast(float, ww[i] << 16);
      s[2 * i + 1] += __builtin_bit_cast(float, ww[i] & 0xFFFF0000u);
    }
  }
  if (t < 32){
    float ls = 0.f;
    for (int ms = 0; ms < S; ++ms)
      ls += l_part[(size_t)(ms * 4 + b) * NN + nin + t];
    inv_sm[t] = 1.0f / ls;
  }
  __syncthreads();

  {
    const float inv = inv_sm[row];
    uint4 pk;
    pk.x = cvtpk(s[0] * inv, s[1] * inv);
    pk.y = cvtpk(s[2] * inv, s[3] * inv);
    pk.z = cvtpk(s[4] * inv, s[5] * inv);
    pk.w = cvtpk(s[6] * inv, s[7] * inv);
    *(uint4*)((char*)y_sm + ((row * 128 + ch * 16) ^ ((row & 7) << 4))) = pk;
  }
  __syncthreads();

  const int w   = __builtin_amdgcn_readfirstlane(t >> 6);
  const int l   = t & 63;
  const int q   = l & 15;
  const int gg  = l >> 4;
  const int swz = (q & 7) << 4;

  bf16x8 wf[2];
#pragma unroll
  for (int ks = 0; ks < 2; ++ks){
    bf16x8 v;
#pragma unroll
    for (int jj = 0; jj < 8; ++jj)
      v[jj] = (short)f2bf(w_out[(w * 16 + q) * 64 + ks * 32 + gg * 8 + jj]);
    wf[ks] = v;
  }
  f32x4 zacc[2];
  zacc[0] = (f32x4){0.f, 0.f, 0.f, 0.f};
  zacc[1] = (f32x4){0.f, 0.f, 0.f, 0.f};
#pragma unroll
  for (int ks = 0; ks < 2; ++ks)
#pragma unroll
    for (int ns = 0; ns < 2; ++ns){
      const int off = (((ns * 16 + q) * 128) + ks * 64 + gg * 16) ^ swz;
      const bf16x8 yf = *(const bf16x8*)((const char*)y_sm + off);
      zacc[ns] = __builtin_amdgcn_mfma_f32_16x16x32_bf16(wf[ks], yf, zacc[ns], 0, 0, 0);
    }

  float bo[4], sc_[4], bb_[4];
#pragma unroll
  for (int r = 0; r < 4; ++r){
    const int c = w * 16 + gg * 4 + r;
    bo[r]  = b_out[c];
    sc_[r] = bn_gamma[c] * 0.99999500003749969f;  // 1/sqrt(1+1e-5)
    bb_[r] = bn_beta[c];
  }
#pragma unroll
  for (int ns = 0; ns < 2; ++ns)
#pragma unroll
    for (int r = 0; r < 4; ++r){
      const int c  = w * 16 + gg * 4 + r;
      const int ng = nin + ns * 16 + q;
      const size_t idx = ((size_t)(b * 64 + c)) * NN + ng;
      float z = zacc[ns][r] + bo[r];
      z = fmaxf(z, 0.0f);
      z = z * sc_[r] + bb_[r];
      out[idx] = x[idx] + z;
    }
}

// ---------------------------------------------------------------------------
extern "C" void kernel_launch(void* const* d_in, const int* in_sizes, int n_in,
                              void* d_out, int out_size, void* d_ws, size_t ws_size,
                              hipStream_t stream)
{
  (void)in_sizes; (void)n_in; (void)out_size;
  const float* x        = (const float*)d_in[0];
  const float* w_theta  = (const float*)d_in[1];
  const float* b_theta  = (const float*)d_in[2];
  const float* w_phi    = (const float*)d_in[3];
  const float* b_phi    = (const float*)d_in[4];
  const float* w_g      = (const float*)d_in[5];
  const float* b_g      = (const float*)d_in[6];
  const float* w_out    = (const float*)d_in[7];
  const float* b_out    = (const float*)d_in[8];
  const float* bn_gamma = (const float*)d_in[9];
  const float* bn_beta  = (const float*)d_in[10];
  float* out = (float*)d_out;

  u16* theta_t = (u16*)d_ws;                       // 2 MB
  u16* phi_t   = theta_t + (size_t)4 * NN * 64;    // 2 MB
  u16* gbuf    = phi_t   + (size_t)4 * NN * 64;    // 2 MB
  char* after  = (char*)(gbuf + (size_t)4 * NN * 64);
  const size_t used = (size_t)(after - (char*)d_ws);
  const size_t perS = (size_t)4 * NN * 64 * 2 + (size_t)4 * NN * 4; // ~2.16 MB

  int S = 1;
  if      (ws_size >= used + 8 * perS) S = 8;
  else if (ws_size >= used + 4 * perS) S = 4;
  else if (ws_size >= used + 2 * perS) S = 2;
  u16*   y_part = (u16*)after;
  float* l_part = (float*)(y_part + (size_t)S * 4 * NN * 64);

  proj_kernel<<<512, 256, 0, stream>>>(x, w_theta, b_theta, w_phi, b_phi,
                                       w_g, b_g, theta_t, phi_t, gbuf);
  if (S == 8)
    attn_kernel<8><<<512, 512, 0, stream>>>(theta_t, phi_t, gbuf, y_part, l_part);
  else if (S == 4)
    attn_kernel<16><<<256, 512, 0, stream>>>(theta_t, phi_t, gbuf, y_part, l_part);
  else if (S == 2)
    attn_kernel<32><<<128, 512, 0, stream>>>(theta_t, phi_t, gbuf, y_part, l_part);
  else
    attn_kernel<64><<<64, 512, 0, stream>>>(theta_t, phi_t, gbuf, y_part, l_part);
  combine_kernel<<<512, 256, 0, stream>>>(y_part, l_part, x, w_out, b_out,
                                          bn_gamma, bn_beta, out, S);
}

// Round 12
// 49.702 us; speedup vs baseline: 6.2039x; 1.0023x over previous
//
#include <hip/hip_runtime.h>

typedef __attribute__((ext_vector_type(4))) float f32x4;
typedef __attribute__((ext_vector_type(16))) float f32x16;
typedef __attribute__((ext_vector_type(8))) short bf16x8;
typedef unsigned short u16;
typedef unsigned int u32;

constexpr int NN = 4096;   // H*W

__device__ __forceinline__ u16 f2bf(float f){
  u32 u = __builtin_bit_cast(u32, f);
  u += 0x7FFFu + ((u >> 16) & 1u);          // round-to-nearest-even
  return (u16)(u >> 16);
}
__device__ __forceinline__ u32 cvtpk(float lo, float hi){
  u32 r;
  asm("v_cvt_pk_bf16_f32 %0, %1, %2" : "=v"(r) : "v"(lo), "v"(hi));
  return r;
}
__device__ __forceinline__ float fexp2(float x){
  float r;
  asm("v_exp_f32 %0, %1" : "=v"(r) : "v"(x));
  return r;
}
__device__ __forceinline__ void async16(void* lds, const void* g){
  __builtin_amdgcn_global_load_lds((const __attribute__((address_space(1))) void*)g,
                                   (__attribute__((address_space(3))) void*)lds,
                                   16, 0, 0);
}

// ---------------------------------------------------------------------------
// proj (R9): 512 blocks (2/CU -> 2 waves/SIMD TLP). Block = (batch, n-chunk,
// o-half). 4 waves x 8 outputs. Weights LDS-staged (48 KB).
// theta gets *log2e folded in. theta_t/phi_t: [b][n][o] bf16; g: [b][o][n].
// ---------------------------------------------------------------------------
__global__ __launch_bounds__(256) void proj_kernel(
    const float* __restrict__ x,
    const float* __restrict__ wth, const float* __restrict__ bth,
    const float* __restrict__ wph, const float* __restrict__ bph,
    const float* __restrict__ wg,  const float* __restrict__ bg,
    u16* __restrict__ theta_t, u16* __restrict__ phi_t, u16* __restrict__ gbuf)
{
  __shared__ float Wsm[3 * 4096];   // 48 KB
  __shared__ float Bsm[3 * 64];

  const int t = threadIdx.x;
#pragma unroll
  for (int i = 0; i < 4; ++i){
    ((float4*)Wsm)[i * 256 + t]            = ((const float4*)wth)[i * 256 + t];
    ((float4*)(Wsm + 4096))[i * 256 + t]   = ((const float4*)wph)[i * 256 + t];
    ((float4*)(Wsm + 8192))[i * 256 + t]   = ((const float4*)wg)[i * 256 + t];
  }
  if (t < 64){ Bsm[t] = bth[t]; Bsm[64 + t] = bph[t]; Bsm[128 + t] = bg[t]; }

  const int bid  = blockIdx.x;
  const int b    = bid >> 7;
  const int half = (bid >> 6) & 1;           // o-half
  const int n    = (bid & 63) * 64 + (t & 63);
  const int w    = __builtin_amdgcn_readfirstlane(t >> 6);
  const int ob   = half * 32 + w * 8;        // this wave's 8-output base

  const float* xb = x + ((size_t)b * 64) * NN + n;
  float xr[64];
#pragma unroll
  for (int c = 0; c < 64; ++c) xr[c] = xb[(size_t)c * NN];

  __syncthreads();

  for (int mat = 0; mat < 3; ++mat){
    const float* Wm = Wsm + mat * 4096 + ob * 64;
    float acc[8];
#pragma unroll
    for (int oo = 0; oo < 8; ++oo) acc[oo] = Bsm[mat * 64 + ob + oo];
#pragma unroll
    for (int c4 = 0; c4 < 16; ++c4)
#pragma unroll
      for (int oo = 0; oo < 8; ++oo){
        const float4 wv = *(const float4*)&Wm[oo * 64 + c4 * 4];  // wave-broadcast
        acc[oo] = fmaf(wv.x, xr[4 * c4],     acc[oo]);
        acc[oo] = fmaf(wv.y, xr[4 * c4 + 1], acc[oo]);
        acc[oo] = fmaf(wv.z, xr[4 * c4 + 2], acc[oo]);
        acc[oo] = fmaf(wv.w, xr[4 * c4 + 3], acc[oo]);
      }
    if (mat == 0){
#pragma unroll
      for (int oo = 0; oo < 8; ++oo) acc[oo] *= 1.44269504088896340736f;
    }
    if (mat < 2){
      uint4 pk;
      pk.x = cvtpk(acc[0], acc[1]); pk.y = cvtpk(acc[2], acc[3]);
      pk.z = cvtpk(acc[4], acc[5]); pk.w = cvtpk(acc[6], acc[7]);
      u16* base = (mat == 0) ? theta_t : phi_t;
      *(uint4*)(base + ((size_t)(b * NN + n)) * 64 + ob) = pk;
    } else {
#pragma unroll
      for (int oo = 0; oo < 8; ++oo)
        gbuf[((size_t)(b * 64 + ob + oo)) * NN + n] = f2bf(acc[oo]);
    }
  }
}

// ---------------------------------------------------------------------------
// attn (R9 + __syncthreads): 32x32x16 MFMA flash, single-barrier-per-tile
// {vmcnt(0); syncthreads; STAGE(t+1); compute(t)}. BM=256 (8 waves x 32 rows),
// m-split S, XCD-aware bijective swizzle. LDS 32KB -> 4 blocks/CU.
// ---------------------------------------------------------------------------
template<int TPB>
__global__ __launch_bounds__(512, 4) void attn_kernel(
    const u16* __restrict__ theta_t, const u16* __restrict__ phi_t,
    const u16* __restrict__ gbuf,
    u16* __restrict__ y_part, float* __restrict__ l_part)
{
  __shared__ u16 phi_sm[2][64 * 64];  // [m_loc][o], XOR-swizzled
  __shared__ u16 g_sm[2][64 * 64];    // [o][m_loc], XOR-swizzled

  const int j   = blockIdx.x;
  const int cpx = gridDim.x >> 3;
  const int lb  = (j & 7) * cpx + (j >> 3);   // bijective (grid % 8 == 0)

  const int ms  = lb >> 6;            // m-split index
  const int pr  = lb & 63;
  const int b   = pr >> 4;
  const int n0  = (pr & 15) * 256;

  const int tid = threadIdx.x;
  const int w   = __builtin_amdgcn_readfirstlane(tid >> 6); // 0..7
  const int l   = tid & 63;
  const int cc  = l & 31;
  const int h   = l >> 5;
  const int sw  = (cc & 7) << 4;
  const int rb  = cc * 128;

  const u16* thb = theta_t + (size_t)b * NN * 64;

  bf16x8 tf[4];
#pragma unroll
  for (int ks = 0; ks < 4; ++ks)
    tf[ks] = *(const bf16x8*)(thb + (size_t)(n0 + w * 32 + cc) * 64 + ks * 16 + h * 8);

  const int m0 = ms * TPB;
  const int r8 = l >> 3;
  const int c8 = l & 7;
  const u16* phi_src = phi_t + (size_t)b * NN * 64
                     + (size_t)(m0 * 64 + w * 8 + r8) * 64 + (c8 ^ r8) * 8;
  const u16* g_src   = gbuf + (size_t)b * 64 * NN
                     + (size_t)(w * 8 + r8) * NN + m0 * 64 + (c8 ^ r8) * 8;

  f32x16 yacc0, yacc1;
#pragma unroll
  for (int i = 0; i < 16; ++i){ yacc0[i] = 0.f; yacc1[i] = 0.f; }
  float lacc = 0.f;

  // prologue: stage tile 0
  async16(&phi_sm[0][w * 512], phi_src);
  async16(&g_sm[0][w * 512],   g_src);
  phi_src += 4096; g_src += 64;

#pragma unroll 2
  for (int it = 0; it < TPB; ++it){
    const int cur = it & 1;
    // own in-flight loads for tile `it` must be in LDS before the barrier
    asm volatile("s_waitcnt vmcnt(0)" ::: "memory");
    __syncthreads();                  // true barrier + compiler fence
    if (it < TPB - 1){
      // stage t+1 into the buffer freed at this barrier; hides under compute
      async16(&phi_sm[cur ^ 1][w * 512], phi_src);
      async16(&g_sm[cur ^ 1][w * 512],   g_src);
      phi_src += 4096; g_src += 64;
    }

    const char* phiB = (const char*)&phi_sm[cur][0];
    const char* gB   = (const char*)&g_sm[cur][0];

#pragma unroll
    for (int tt = 0; tt < 2; ++tt){
      __builtin_amdgcn_s_setprio(1);
      f32x16 p;
#pragma unroll
      for (int i = 0; i < 16; ++i) p[i] = 0.f;
#pragma unroll
      for (int ks = 0; ks < 4; ++ks)
        p = __builtin_amdgcn_mfma_f32_32x32x16_bf16(
              *(const bf16x8*)(phiB + tt * 4096 + rb + ((ks * 32 + h * 16) ^ sw)),
              tf[ks], p, 0, 0, 0);
      __builtin_amdgcn_s_setprio(0);

      u32 wpk[4][2];
#pragma unroll
      for (int rq = 0; rq < 4; ++rq){
        const float e0 = fexp2(p[4 * rq + 0]), e1 = fexp2(p[4 * rq + 1]);
        const float e2 = fexp2(p[4 * rq + 2]), e3 = fexp2(p[4 * rq + 3]);
        lacc += (e0 + e1) + (e2 + e3);
        wpk[rq][0] = cvtpk(e0, e1);
        wpk[rq][1] = cvtpk(e2, e3);
      }

      __builtin_amdgcn_s_setprio(1);
#pragma unroll
      for (int par = 0; par < 2; ++par){
        u32 A0 = wpk[2 * par][0],     A1 = wpk[2 * par][1];
        u32 B0 = wpk[2 * par + 1][0], B1 = wpk[2 * par + 1][1];
        asm("v_permlane32_swap_b32 %0, %1" : "+v"(A0), "+v"(B0));
        asm("v_permlane32_swap_b32 %0, %1" : "+v"(A1), "+v"(B1));
        union { u32 u[4]; bf16x8 v; } pw;
        pw.u[0] = A0; pw.u[1] = A1; pw.u[2] = B0; pw.u[3] = B1;
        const int s   = tt * 2 + par;
        const int gof = (s * 32 + h * 16) ^ sw;
        yacc0 = __builtin_amdgcn_mfma_f32_32x32x16_bf16(
                  pw.v, *(const bf16x8*)(gB + rb + gof), yacc0, 0, 0, 0);
        yacc1 = __builtin_amdgcn_mfma_f32_32x32x16_bf16(
                  pw.v, *(const bf16x8*)(gB + 4096 + rb + gof), yacc1, 0, 0, 0);
      }
      __builtin_amdgcn_s_setprio(0);
    }
  }

  // cross-half l combine
  {
    u32 la = __builtin_bit_cast(u32, lacc), lb2 = la;
    asm("v_permlane32_swap_b32 %0, %1" : "+v"(la), "+v"(lb2));
    const float ltot = __builtin_bit_cast(float, la) + __builtin_bit_cast(float, lb2);
    if (l < 32)
      l_part[(size_t)(ms * 4 + b) * NN + n0 + w * 32 + cc] = ltot;
  }

  u16* yp = y_part + ((size_t)(ms * 4 + b) * NN + n0 + w * 32) * 64 + cc;
#pragma unroll
  for (int r = 0; r < 16; ++r){
    const int nl = (r & 3) + 8 * (r >> 2) + 4 * h;
    yp[(size_t)nl * 64]      = f2bf(yacc0[r]);
    yp[(size_t)nl * 64 + 32] = f2bf(yacc1[r]);
  }
}

// ---------------------------------------------------------------------------
// combine (R9): 512 blocks x 32 rows. Sum S bf16 partials, normalize,
// w_out GEMM + bias/ReLU/BN + residual.
// ---------------------------------------------------------------------------
__global__ __launch_bounds__(256) void combine_kernel(
    const u16* __restrict__ y_part, const float* __restrict__ l_part,
    const float* __restrict__ x,
    const float* __restrict__ w_out, const float* __restrict__ b_out,
    const float* __restrict__ bn_gamma, const float* __restrict__ bn_beta,
    float* __restrict__ out, int S)
{
  __shared__ u16 y_sm[32 * 64];       // [row][o] bf16, swizzled
  __shared__ float inv_sm[32];

  const int cb   = blockIdx.x;            // 0..511
  const int b    = cb >> 7;
  const int nin  = (cb & 127) * 32;       // row base within batch
  const int t    = threadIdx.x;
  const int row  = t >> 3;                // 0..31
  const int ch   = t & 7;                 // 16B chunk (8 bf16)

  float s[8] = {0.f,0.f,0.f,0.f,0.f,0.f,0.f,0.f};
  for (int ms = 0; ms < S; ++ms){
    const u16* src = y_part + ((size_t)(ms * 4 + b) * NN + nin + row) * 64 + ch * 8;
    const uint4 v = *(const uint4*)src;
    const u32 ww[4] = {v.x, v.y, v.z, v.w};
#pragma unroll
    for (int i = 0; i < 4; ++i){
      s[2 * i]     += __builtin_bit_cast(float, ww[i] << 16);
      s[2 * i + 1] += __builtin_bit_cast(float, ww[i] & 0xFFFF0000u);
    }
  }
  if (t < 32){
    float ls = 0.f;
    for (int ms = 0; ms < S; ++ms)
      ls += l_part[(size_t)(ms * 4 + b) * NN + nin + t];
    inv_sm[t] = 1.0f / ls;
  }
  __syncthreads();

  {
    const float inv = inv_sm[row];
    uint4 pk;
    pk.x = cvtpk(s[0] * inv, s[1] * inv);
    pk.y = cvtpk(s[2] * inv, s[3] * inv);
    pk.z = cvtpk(s[4] * inv, s[5] * inv);
    pk.w = cvtpk(s[6] * inv, s[7] * inv);
    *(uint4*)((char*)y_sm + ((row * 128 + ch * 16) ^ ((row & 7) << 4))) = pk;
  }
  __syncthreads();

  const int w   = __builtin_amdgcn_readfirstlane(t >> 6);
  const int l   = t & 63;
  const int q   = l & 15;
  const int gg  = l >> 4;
  const int swz = (q & 7) << 4;

  bf16x8 wf[2];
#pragma unroll
  for (int ks = 0; ks < 2; ++ks){
    bf16x8 v;
#pragma unroll
    for (int jj = 0; jj < 8; ++jj)
      v[jj] = (short)f2bf(w_out[(w * 16 + q) * 64 + ks * 32 + gg * 8 + jj]);
    wf[ks] = v;
  }
  f32x4 zacc[2];
  zacc[0] = (f32x4){0.f, 0.f, 0.f, 0.f};
  zacc[1] = (f32x4){0.f, 0.f, 0.f, 0.f};
#pragma unroll
  for (int ks = 0; ks < 2; ++ks)
#pragma unroll
    for (int ns = 0; ns < 2; ++ns){
      const int off = (((ns * 16 + q) * 128) + ks * 64 + gg * 16) ^ swz;
      const bf16x8 yf = *(const bf16x8*)((const char*)y_sm + off);
      zacc[ns] = __builtin_amdgcn_mfma_f32_16x16x32_bf16(wf[ks], yf, zacc[ns], 0, 0, 0);
    }

  float bo[4], sc_[4], bb_[4];
#pragma unroll
  for (int r = 0; r < 4; ++r){
    const int c = w * 16 + gg * 4 + r;
    bo[r]  = b_out[c];
    sc_[r] = bn_gamma[c] * 0.99999500003749969f;  // 1/sqrt(1+1e-5)
    bb_[r] = bn_beta[c];
  }
#pragma unroll
  for (int ns = 0; ns < 2; ++ns)
#pragma unroll
    for (int r = 0; r < 4; ++r){
      const int c  = w * 16 + gg * 4 + r;
      const int ng = nin + ns * 16 + q;
      const size_t idx = ((size_t)(b * 64 + c)) * NN + ng;
      float z = zacc[ns][r] + bo[r];
      z = fmaxf(z, 0.0f);
      z = z * sc_[r] + bb_[r];
      out[idx] = x[idx] + z;
    }
}

// ---------------------------------------------------------------------------
extern "C" void kernel_launch(void* const* d_in, const int* in_sizes, int n_in,
                              void* d_out, int out_size, void* d_ws, size_t ws_size,
                              hipStream_t stream)
{
  (void)in_sizes; (void)n_in; (void)out_size;
  const float* x        = (const float*)d_in[0];
  const float* w_theta  = (const float*)d_in[1];
  const float* b_theta  = (const float*)d_in[2];
  const float* w_phi    = (const float*)d_in[3];
  const float* b_phi    = (const float*)d_in[4];
  const float* w_g      = (const float*)d_in[5];
  const float* b_g      = (const float*)d_in[6];
  const float* w_out    = (const float*)d_in[7];
  const float* b_out    = (const float*)d_in[8];
  const float* bn_gamma = (const float*)d_in[9];
  const float* bn_beta  = (const float*)d_in[10];
  float* out = (float*)d_out;

  u16* theta_t = (u16*)d_ws;                       // 2 MB
  u16* phi_t   = theta_t + (size_t)4 * NN * 64;    // 2 MB
  u16* gbuf    = phi_t   + (size_t)4 * NN * 64;    // 2 MB
  char* after  = (char*)(gbuf + (size_t)4 * NN * 64);
  const size_t used = (size_t)(after - (char*)d_ws);
  const size_t perS = (size_t)4 * NN * 64 * 2 + (size_t)4 * NN * 4; // ~2.16 MB

  int S = 1;
  if      (ws_size >= used + 8 * perS) S = 8;
  else if (ws_size >= used + 4 * perS) S = 4;
  else if (ws_size >= used + 2 * perS) S = 2;
  u16*   y_part = (u16*)after;
  float* l_part = (float*)(y_part + (size_t)S * 4 * NN * 64);

  proj_kernel<<<512, 256, 0, stream>>>(x, w_theta, b_theta, w_phi, b_phi,
                                       w_g, b_g, theta_t, phi_t, gbuf);
  if (S == 8)
    attn_kernel<8><<<512, 512, 0, stream>>>(theta_t, phi_t, gbuf, y_part, l_part);
  else if (S == 4)
    attn_kernel<16><<<256, 512, 0, stream>>>(theta_t, phi_t, gbuf, y_part, l_part);
  else if (S == 2)
    attn_kernel<32><<<128, 512, 0, stream>>>(theta_t, phi_t, gbuf, y_part, l_part);
  else
    attn_kernel<64><<<64, 512, 0, stream>>>(theta_t, phi_t, gbuf, y_part, l_part);
  combine_kernel<<<512, 256, 0, stream>>>(y_part, l_part, x, w_out, b_out,
                                          bn_gamma, bn_beta, out, S);
}

// Round 14
// 49.290 us; speedup vs baseline: 6.2558x; 1.0084x over previous
//
#include <hip/hip_runtime.h>

typedef __attribute__((ext_vector_type(4))) float f32x4;
typedef __attribute__((ext_vector_type(16))) float f32x16;
typedef __attribute__((ext_vector_type(8))) short bf16x8;
typedef unsigned short u16;
typedef unsigned int u32;

constexpr int NN = 4096;   // H*W

__device__ __forceinline__ u16 f2bf(float f){
  u32 u = __builtin_bit_cast(u32, f);
  u += 0x7FFFu + ((u >> 16) & 1u);          // round-to-nearest-even
  return (u16)(u >> 16);
}
__device__ __forceinline__ u32 cvtpk(float lo, float hi){
  u32 r;
  asm("v_cvt_pk_bf16_f32 %0, %1, %2" : "=v"(r) : "v"(lo), "v"(hi));
  return r;
}
__device__ __forceinline__ float fexp2(float x){
  float r;
  asm("v_exp_f32 %0, %1" : "=v"(r) : "v"(x));
  return r;
}
__device__ __forceinline__ void async16(void* lds, const void* g){
  __builtin_amdgcn_global_load_lds((const __attribute__((address_space(1))) void*)g,
                                   (__attribute__((address_space(3))) void*)lds,
                                   16, 0, 0);
}

// ---------------------------------------------------------------------------
// proj v8 (exonerated by R11-vs-R13 isolation): 256 blocks x 512 threads
// (8 waves -> 2 waves/SIMD), x read ONCE. Wave w computes o in [w*8, w*8+8)
// for all 3 matrices. theta gets *log2e folded in.
// theta_t/phi_t: [b][n][o] bf16; g: [b][o][n].
// ---------------------------------------------------------------------------
__global__ __launch_bounds__(512) void proj_kernel(
    const float* __restrict__ x,
    const float* __restrict__ wth, const float* __restrict__ bth,
    const float* __restrict__ wph, const float* __restrict__ bph,
    const float* __restrict__ wg,  const float* __restrict__ bg,
    u16* __restrict__ theta_t, u16* __restrict__ phi_t, u16* __restrict__ gbuf)
{
  __shared__ float Wsm[3 * 4096];   // 48 KB
  __shared__ float Bsm[3 * 64];

  const int t = threadIdx.x;
#pragma unroll
  for (int i = 0; i < 6; ++i){
    const int idx = i * 512 + t;             // 0..3071 float4s
    const float4 v = (idx < 1024) ? ((const float4*)wth)[idx]
                   : (idx < 2048) ? ((const float4*)wph)[idx - 1024]
                                  : ((const float4*)wg)[idx - 2048];
    ((float4*)Wsm)[idx] = v;
  }
  if (t < 192) Bsm[t] = (t < 64) ? bth[t] : (t < 128) ? bph[t - 64] : bg[t - 128];

  const int b = blockIdx.x >> 6;
  const int n = (blockIdx.x & 63) * 64 + (t & 63);
  const int w = __builtin_amdgcn_readfirstlane(t >> 6);   // 0..7
  const int ob = w * 8;

  const float* xb = x + ((size_t)b * 64) * NN + n;
  float xr[64];
#pragma unroll
  for (int c = 0; c < 64; ++c) xr[c] = xb[(size_t)c * NN];

  __syncthreads();

  for (int mat = 0; mat < 3; ++mat){
    const float* Wm = Wsm + mat * 4096 + ob * 64;
    float acc[8];
#pragma unroll
    for (int oo = 0; oo < 8; ++oo) acc[oo] = Bsm[mat * 64 + ob + oo];
#pragma unroll
    for (int c4 = 0; c4 < 16; ++c4)
#pragma unroll
      for (int oo = 0; oo < 8; ++oo){
        const float4 wv = *(const float4*)&Wm[oo * 64 + c4 * 4];  // wave-broadcast
        acc[oo] = fmaf(wv.x, xr[4 * c4],     acc[oo]);
        acc[oo] = fmaf(wv.y, xr[4 * c4 + 1], acc[oo]);
        acc[oo] = fmaf(wv.z, xr[4 * c4 + 2], acc[oo]);
        acc[oo] = fmaf(wv.w, xr[4 * c4 + 3], acc[oo]);
      }
    if (mat == 0){
#pragma unroll
      for (int oo = 0; oo < 8; ++oo) acc[oo] *= 1.44269504088896340736f;
    }
    if (mat < 2){
      uint4 pk;
      pk.x = cvtpk(acc[0], acc[1]); pk.y = cvtpk(acc[2], acc[3]);
      pk.z = cvtpk(acc[4], acc[5]); pk.w = cvtpk(acc[6], acc[7]);
      u16* base = (mat == 0) ? theta_t : phi_t;
      *(uint4*)(base + ((size_t)(b * NN + n)) * 64 + ob) = pk;
    } else {
#pragma unroll
      for (int oo = 0; oo < 8; ++oo)
        gbuf[((size_t)(b * 64 + ob + oo)) * NN + n] = f2bf(acc[oo]);
    }
  }
}

// ---------------------------------------------------------------------------
// attn (R12, unchanged — validated): 32x32x16 MFMA flash, single-tile-per-
// barrier {vmcnt(0); syncthreads; STAGE(t+1); compute(t)}. BM=256 (8 waves x
// 32 rows), m-split S, XCD-aware bijective swizzle. LDS 32KB -> 4 blocks/CU.
// NOTE: pair-staging (2 tiles/barrier) is PROVEN BROKEN (R10/R11/R13) — do
// not reintroduce.
// ---------------------------------------------------------------------------
template<int TPB>
__global__ __launch_bounds__(512, 4) void attn_kernel(
    const u16* __restrict__ theta_t, const u16* __restrict__ phi_t,
    const u16* __restrict__ gbuf,
    u16* __restrict__ y_part, float* __restrict__ l_part)
{
  __shared__ u16 phi_sm[2][64 * 64];  // [m_loc][o], XOR-swizzled
  __shared__ u16 g_sm[2][64 * 64];    // [o][m_loc], XOR-swizzled

  const int j   = blockIdx.x;
  const int cpx = gridDim.x >> 3;
  const int lb  = (j & 7) * cpx + (j >> 3);   // bijective (grid % 8 == 0)

  const int ms  = lb >> 6;            // m-split index
  const int pr  = lb & 63;
  const int b   = pr >> 4;
  const int n0  = (pr & 15) * 256;

  const int tid = threadIdx.x;
  const int w   = __builtin_amdgcn_readfirstlane(tid >> 6); // 0..7
  const int l   = tid & 63;
  const int cc  = l & 31;
  const int h   = l >> 5;
  const int sw  = (cc & 7) << 4;
  const int rb  = cc * 128;

  const u16* thb = theta_t + (size_t)b * NN * 64;

  bf16x8 tf[4];
#pragma unroll
  for (int ks = 0; ks < 4; ++ks)
    tf[ks] = *(const bf16x8*)(thb + (size_t)(n0 + w * 32 + cc) * 64 + ks * 16 + h * 8);

  const int m0 = ms * TPB;
  const int r8 = l >> 3;
  const int c8 = l & 7;
  const u16* phi_src = phi_t + (size_t)b * NN * 64
                     + (size_t)(m0 * 64 + w * 8 + r8) * 64 + (c8 ^ r8) * 8;
  const u16* g_src   = gbuf + (size_t)b * 64 * NN
                     + (size_t)(w * 8 + r8) * NN + m0 * 64 + (c8 ^ r8) * 8;

  f32x16 yacc0, yacc1;
#pragma unroll
  for (int i = 0; i < 16; ++i){ yacc0[i] = 0.f; yacc1[i] = 0.f; }
  float lacc = 0.f;

  // prologue: stage tile 0
  async16(&phi_sm[0][w * 512], phi_src);
  async16(&g_sm[0][w * 512],   g_src);
  phi_src += 4096; g_src += 64;

#pragma unroll 2
  for (int it = 0; it < TPB; ++it){
    const int cur = it & 1;
    // own in-flight loads for tile `it` must be in LDS before the barrier
    asm volatile("s_waitcnt vmcnt(0)" ::: "memory");
    __syncthreads();                  // true barrier + compiler fence
    if (it < TPB - 1){
      // stage t+1 into the buffer freed at this barrier; hides under compute
      async16(&phi_sm[cur ^ 1][w * 512], phi_src);
      async16(&g_sm[cur ^ 1][w * 512],   g_src);
      phi_src += 4096; g_src += 64;
    }

    const char* phiB = (const char*)&phi_sm[cur][0];
    const char* gB   = (const char*)&g_sm[cur][0];

#pragma unroll
    for (int tt = 0; tt < 2; ++tt){
      __builtin_amdgcn_s_setprio(1);
      f32x16 p;
#pragma unroll
      for (int i = 0; i < 16; ++i) p[i] = 0.f;
#pragma unroll
      for (int ks = 0; ks < 4; ++ks)
        p = __builtin_amdgcn_mfma_f32_32x32x16_bf16(
              *(const bf16x8*)(phiB + tt * 4096 + rb + ((ks * 32 + h * 16) ^ sw)),
              tf[ks], p, 0, 0, 0);
      __builtin_amdgcn_s_setprio(0);

      u32 wpk[4][2];
#pragma unroll
      for (int rq = 0; rq < 4; ++rq){
        const float e0 = fexp2(p[4 * rq + 0]), e1 = fexp2(p[4 * rq + 1]);
        const float e2 = fexp2(p[4 * rq + 2]), e3 = fexp2(p[4 * rq + 3]);
        lacc += (e0 + e1) + (e2 + e3);
        wpk[rq][0] = cvtpk(e0, e1);
        wpk[rq][1] = cvtpk(e2, e3);
      }

      __builtin_amdgcn_s_setprio(1);
#pragma unroll
      for (int par = 0; par < 2; ++par){
        u32 A0 = wpk[2 * par][0],     A1 = wpk[2 * par][1];
        u32 B0 = wpk[2 * par + 1][0], B1 = wpk[2 * par + 1][1];
        asm("v_permlane32_swap_b32 %0, %1" : "+v"(A0), "+v"(B0));
        asm("v_permlane32_swap_b32 %0, %1" : "+v"(A1), "+v"(B1));
        union { u32 u[4]; bf16x8 v; } pw;
        pw.u[0] = A0; pw.u[1] = A1; pw.u[2] = B0; pw.u[3] = B1;
        const int s   = tt * 2 + par;
        const int gof = (s * 32 + h * 16) ^ sw;
        yacc0 = __builtin_amdgcn_mfma_f32_32x32x16_bf16(
                  pw.v, *(const bf16x8*)(gB + rb + gof), yacc0, 0, 0, 0);
        yacc1 = __builtin_amdgcn_mfma_f32_32x32x16_bf16(
                  pw.v, *(const bf16x8*)(gB + 4096 + rb + gof), yacc1, 0, 0, 0);
      }
      __builtin_amdgcn_s_setprio(0);
    }
  }

  // cross-half l combine
  {
    u32 la = __builtin_bit_cast(u32, lacc), lb2 = la;
    asm("v_permlane32_swap_b32 %0, %1" : "+v"(la), "+v"(lb2));
    const float ltot = __builtin_bit_cast(float, la) + __builtin_bit_cast(float, lb2);
    if (l < 32)
      l_part[(size_t)(ms * 4 + b) * NN + n0 + w * 32 + cc] = ltot;
  }

  u16* yp = y_part + ((size_t)(ms * 4 + b) * NN + n0 + w * 32) * 64 + cc;
#pragma unroll
  for (int r = 0; r < 16; ++r){
    const int nl = (r & 3) + 8 * (r >> 2) + 4 * h;
    yp[(size_t)nl * 64]      = f2bf(yacc0[r]);
    yp[(size_t)nl * 64 + 32] = f2bf(yacc1[r]);
  }
}

// ---------------------------------------------------------------------------
// combine (R12, unchanged): 512 blocks x 32 rows. Sum S bf16 partials,
// normalize, w_out GEMM + bias/ReLU/BN + residual.
// ---------------------------------------------------------------------------
__global__ __launch_bounds__(256) void combine_kernel(
    const u16* __restrict__ y_part, const float* __restrict__ l_part,
    const float* __restrict__ x,
    const float* __restrict__ w_out, const float* __restrict__ b_out,
    const float* __restrict__ bn_gamma, const float* __restrict__ bn_beta,
    float* __restrict__ out, int S)
{
  __shared__ u16 y_sm[32 * 64];       // [row][o] bf16, swizzled
  __shared__ float inv_sm[32];

  const int cb   = blockIdx.x;            // 0..511
  const int b    = cb >> 7;
  const int nin  = (cb & 127) * 32;       // row base within batch
  const int t    = threadIdx.x;
  const int row  = t >> 3;                // 0..31
  const int ch   = t & 7;                 // 16B chunk (8 bf16)

  float s[8] = {0.f,0.f,0.f,0.f,0.f,0.f,0.f,0.f};
  for (int ms = 0; ms < S; ++ms){
    const u16* src = y_part + ((size_t)(ms * 4 + b) * NN + nin + row) * 64 + ch * 8;
    const uint4 v = *(const uint4*)src;
    const u32 ww[4] = {v.x, v.y, v.z, v.w};
#pragma unroll
    for (int i = 0; i < 4; ++i){
      s[2 * i]     += __builtin_bit_cast(float, ww[i] << 16);
      s[2 * i + 1] += __builtin_bit_cast(float, ww[i] & 0xFFFF0000u);
    }
  }
  if (t < 32){
    float ls = 0.f;
    for (int ms = 0; ms < S; ++ms)
      ls += l_part[(size_t)(ms * 4 + b) * NN + nin + t];
    inv_sm[t] = 1.0f / ls;
  }
  __syncthreads();

  {
    const float inv = inv_sm[row];
    uint4 pk;
    pk.x = cvtpk(s[0] * inv, s[1] * inv);
    pk.y = cvtpk(s[2] * inv, s[3] * inv);
    pk.z = cvtpk(s[4] * inv, s[5] * inv);
    pk.w = cvtpk(s[6] * inv, s[7] * inv);
    *(uint4*)((char*)y_sm + ((row * 128 + ch * 16) ^ ((row & 7) << 4))) = pk;
  }
  __syncthreads();

  const int w   = __builtin_amdgcn_readfirstlane(t >> 6);
  const int l   = t & 63;
  const int q   = l & 15;
  const int gg  = l >> 4;
  const int swz = (q & 7) << 4;

  bf16x8 wf[2];
#pragma unroll
  for (int ks = 0; ks < 2; ++ks){
    bf16x8 v;
#pragma unroll
    for (int jj = 0; jj < 8; ++jj)
      v[jj] = (short)f2bf(w_out[(w * 16 + q) * 64 + ks * 32 + gg * 8 + jj]);
    wf[ks] = v;
  }
  f32x4 zacc[2];
  zacc[0] = (f32x4){0.f, 0.f, 0.f, 0.f};
  zacc[1] = (f32x4){0.f, 0.f, 0.f, 0.f};
#pragma unroll
  for (int ks = 0; ks < 2; ++ks)
#pragma unroll
    for (int ns = 0; ns < 2; ++ns){
      const int off = (((ns * 16 + q) * 128) + ks * 64 + gg * 16) ^ swz;
      const bf16x8 yf = *(const bf16x8*)((const char*)y_sm + off);
      zacc[ns] = __builtin_amdgcn_mfma_f32_16x16x32_bf16(wf[ks], yf, zacc[ns], 0, 0, 0);
    }

  float bo[4], sc_[4], bb_[4];
#pragma unroll
  for (int r = 0; r < 4; ++r){
    const int c = w * 16 + gg * 4 + r;
    bo[r]  = b_out[c];
    sc_[r] = bn_gamma[c] * 0.99999500003749969f;  // 1/sqrt(1+1e-5)
    bb_[r] = bn_beta[c];
  }
#pragma unroll
  for (int ns = 0; ns < 2; ++ns)
#pragma unroll
    for (int r = 0; r < 4; ++r){
      const int c  = w * 16 + gg * 4 + r;
      const int ng = nin + ns * 16 + q;
      const size_t idx = ((size_t)(b * 64 + c)) * NN + ng;
      float z = zacc[ns][r] + bo[r];
      z = fmaxf(z, 0.0f);
      z = z * sc_[r] + bb_[r];
      out[idx] = x[idx] + z;
    }
}

// ---------------------------------------------------------------------------
extern "C" void kernel_launch(void* const* d_in, const int* in_sizes, int n_in,
                              void* d_out, int out_size, void* d_ws, size_t ws_size,
                              hipStream_t stream)
{
  (void)in_sizes; (void)n_in; (void)out_size;
  const float* x        = (const float*)d_in[0];
  const float* w_theta  = (const float*)d_in[1];
  const float* b_theta  = (const float*)d_in[2];
  const float* w_phi    = (const float*)d_in[3];
  const float* b_phi    = (const float*)d_in[4];
  const float* w_g      = (const float*)d_in[5];
  const float* b_g      = (const float*)d_in[6];
  const float* w_out    = (const float*)d_in[7];
  const float* b_out    = (const float*)d_in[8];
  const float* bn_gamma = (const float*)d_in[9];
  const float* bn_beta  = (const float*)d_in[10];
  float* out = (float*)d_out;

  u16* theta_t = (u16*)d_ws;                       // 2 MB
  u16* phi_t   = theta_t + (size_t)4 * NN * 64;    // 2 MB
  u16* gbuf    = phi_t   + (size_t)4 * NN * 64;    // 2 MB
  char* after  = (char*)(gbuf + (size_t)4 * NN * 64);
  const size_t used = (size_t)(after - (char*)d_ws);
  const size_t perS = (size_t)4 * NN * 64 * 2 + (size_t)4 * NN * 4; // ~2.16 MB

  int S = 1;
  if      (ws_size >= used + 8 * perS) S = 8;
  else if (ws_size >= used + 4 * perS) S = 4;
  else if (ws_size >= used + 2 * perS) S = 2;
  u16*   y_part = (u16*)after;
  float* l_part = (float*)(y_part + (size_t)S * 4 * NN * 64);

  proj_kernel<<<256, 512, 0, stream>>>(x, w_theta, b_theta, w_phi, b_phi,
                                       w_g, b_g, theta_t, phi_t, gbuf);
  if (S == 8)
    attn_kernel<8><<<512, 512, 0, stream>>>(theta_t, phi_t, gbuf, y_part, l_part);
  else if (S == 4)
    attn_kernel<16><<<256, 512, 0, stream>>>(theta_t, phi_t, gbuf, y_part, l_part);
  else if (S == 2)
    attn_kernel<32><<<128, 512, 0, stream>>>(theta_t, phi_t, gbuf, y_part, l_part);
  else
    attn_kernel<64><<<64, 512, 0, stream>>>(theta_t, phi_t, gbuf, y_part, l_part);
  combine_kernel<<<512, 256, 0, stream>>>(y_part, l_part, x, w_out, b_out,
                                          bn_gamma, bn_beta, out, S);
}

// Round 15
// 49.213 us; speedup vs baseline: 6.2656x; 1.0016x over previous
//
#include <hip/hip_runtime.h>

typedef __attribute__((ext_vector_type(4))) float f32x4;
typedef __attribute__((ext_vector_type(16))) float f32x16;
typedef __attribute__((ext_vector_type(8))) short bf16x8;
typedef unsigned short u16;
typedef unsigned int u32;

constexpr int NN = 4096;   // H*W

__device__ __forceinline__ u16 f2bf(float f){
  u32 u = __builtin_bit_cast(u32, f);
  u += 0x7FFFu + ((u >> 16) & 1u);          // round-to-nearest-even
  return (u16)(u >> 16);
}
__device__ __forceinline__ u32 cvtpk(float lo, float hi){
  u32 r;
  asm("v_cvt_pk_bf16_f32 %0, %1, %2" : "=v"(r) : "v"(lo), "v"(hi));
  return r;
}
__device__ __forceinline__ float fexp2(float x){
  float r;
  asm("v_exp_f32 %0, %1" : "=v"(r) : "v"(x));
  return r;
}
__device__ __forceinline__ void async16(void* lds, const void* g){
  __builtin_amdgcn_global_load_lds((const __attribute__((address_space(1))) void*)g,
                                   (__attribute__((address_space(3))) void*)lds,
                                   16, 0, 0);
}

// ---------------------------------------------------------------------------
// proj v8 (validated R14): 256 blocks x 512 threads (8 waves -> 2 waves/SIMD),
// x read ONCE. Wave w computes o in [w*8, w*8+8) for all 3 matrices.
// theta gets *log2e folded in. theta_t/phi_t: [b][n][o] bf16; g: [b][o][n].
// ---------------------------------------------------------------------------
__global__ __launch_bounds__(512) void proj_kernel(
    const float* __restrict__ x,
    const float* __restrict__ wth, const float* __restrict__ bth,
    const float* __restrict__ wph, const float* __restrict__ bph,
    const float* __restrict__ wg,  const float* __restrict__ bg,
    u16* __restrict__ theta_t, u16* __restrict__ phi_t, u16* __restrict__ gbuf)
{
  __shared__ float Wsm[3 * 4096];   // 48 KB
  __shared__ float Bsm[3 * 64];

  const int t = threadIdx.x;
#pragma unroll
  for (int i = 0; i < 6; ++i){
    const int idx = i * 512 + t;             // 0..3071 float4s
    const float4 v = (idx < 1024) ? ((const float4*)wth)[idx]
                   : (idx < 2048) ? ((const float4*)wph)[idx - 1024]
                                  : ((const float4*)wg)[idx - 2048];
    ((float4*)Wsm)[idx] = v;
  }
  if (t < 192) Bsm[t] = (t < 64) ? bth[t] : (t < 128) ? bph[t - 64] : bg[t - 128];

  const int b = blockIdx.x >> 6;
  const int n = (blockIdx.x & 63) * 64 + (t & 63);
  const int w = __builtin_amdgcn_readfirstlane(t >> 6);   // 0..7
  const int ob = w * 8;

  const float* xb = x + ((size_t)b * 64) * NN + n;
  float xr[64];
#pragma unroll
  for (int c = 0; c < 64; ++c) xr[c] = xb[(size_t)c * NN];

  __syncthreads();

  for (int mat = 0; mat < 3; ++mat){
    const float* Wm = Wsm + mat * 4096 + ob * 64;
    float acc[8];
#pragma unroll
    for (int oo = 0; oo < 8; ++oo) acc[oo] = Bsm[mat * 64 + ob + oo];
#pragma unroll
    for (int c4 = 0; c4 < 16; ++c4)
#pragma unroll
      for (int oo = 0; oo < 8; ++oo){
        const float4 wv = *(const float4*)&Wm[oo * 64 + c4 * 4];  // wave-broadcast
        acc[oo] = fmaf(wv.x, xr[4 * c4],     acc[oo]);
        acc[oo] = fmaf(wv.y, xr[4 * c4 + 1], acc[oo]);
        acc[oo] = fmaf(wv.z, xr[4 * c4 + 2], acc[oo]);
        acc[oo] = fmaf(wv.w, xr[4 * c4 + 3], acc[oo]);
      }
    if (mat == 0){
#pragma unroll
      for (int oo = 0; oo < 8; ++oo) acc[oo] *= 1.44269504088896340736f;
    }
    if (mat < 2){
      uint4 pk;
      pk.x = cvtpk(acc[0], acc[1]); pk.y = cvtpk(acc[2], acc[3]);
      pk.z = cvtpk(acc[4], acc[5]); pk.w = cvtpk(acc[6], acc[7]);
      u16* base = (mat == 0) ? theta_t : phi_t;
      *(uint4*)(base + ((size_t)(b * NN + n)) * 64 + ob) = pk;
    } else {
#pragma unroll
      for (int oo = 0; oo < 8; ++oo)
        gbuf[((size_t)(b * 64 + ob + oo)) * NN + n] = f2bf(acc[oo]);
    }
  }
}

// ---------------------------------------------------------------------------
// attn (R12/R14 validated): 32x32x16 MFMA flash, single-tile-per-barrier
// {vmcnt(0); syncthreads; STAGE(t+1); compute(t)}. BM=256 (8 waves x 32
// rows), m-split S, XCD-aware bijective swizzle. LDS 32KB.
// NOTE: pair-staging (2 tiles/barrier) is PROVEN BROKEN (R10/R11/R13) — do
// not reintroduce.
// ---------------------------------------------------------------------------
template<int TPB>
__global__ __launch_bounds__(512, 4) void attn_kernel(
    const u16* __restrict__ theta_t, const u16* __restrict__ phi_t,
    const u16* __restrict__ gbuf,
    u16* __restrict__ y_part, float* __restrict__ l_part)
{
  __shared__ u16 phi_sm[2][64 * 64];  // [m_loc][o], XOR-swizzled
  __shared__ u16 g_sm[2][64 * 64];    // [o][m_loc], XOR-swizzled

  const int j   = blockIdx.x;
  const int cpx = gridDim.x >> 3;
  const int lb  = (j & 7) * cpx + (j >> 3);   // bijective (grid % 8 == 0)

  const int ms  = lb >> 6;            // m-split index
  const int pr  = lb & 63;
  const int b   = pr >> 4;
  const int n0  = (pr & 15) * 256;

  const int tid = threadIdx.x;
  const int w   = __builtin_amdgcn_readfirstlane(tid >> 6); // 0..7
  const int l   = tid & 63;
  const int cc  = l & 31;
  const int h   = l >> 5;
  const int sw  = (cc & 7) << 4;
  const int rb  = cc * 128;

  const u16* thb = theta_t + (size_t)b * NN * 64;

  bf16x8 tf[4];
#pragma unroll
  for (int ks = 0; ks < 4; ++ks)
    tf[ks] = *(const bf16x8*)(thb + (size_t)(n0 + w * 32 + cc) * 64 + ks * 16 + h * 8);

  const int m0 = ms * TPB;
  const int r8 = l >> 3;
  const int c8 = l & 7;
  const u16* phi_src = phi_t + (size_t)b * NN * 64
                     + (size_t)(m0 * 64 + w * 8 + r8) * 64 + (c8 ^ r8) * 8;
  const u16* g_src   = gbuf + (size_t)b * 64 * NN
                     + (size_t)(w * 8 + r8) * NN + m0 * 64 + (c8 ^ r8) * 8;

  f32x16 yacc0, yacc1;
#pragma unroll
  for (int i = 0; i < 16; ++i){ yacc0[i] = 0.f; yacc1[i] = 0.f; }
  float lacc = 0.f;

  // prologue: stage tile 0
  async16(&phi_sm[0][w * 512], phi_src);
  async16(&g_sm[0][w * 512],   g_src);
  phi_src += 4096; g_src += 64;

#pragma unroll 2
  for (int it = 0; it < TPB; ++it){
    const int cur = it & 1;
    // own in-flight loads for tile `it` must be in LDS before the barrier
    asm volatile("s_waitcnt vmcnt(0)" ::: "memory");
    __syncthreads();                  // true barrier + compiler fence
    if (it < TPB - 1){
      // stage t+1 into the buffer freed at this barrier; hides under compute
      async16(&phi_sm[cur ^ 1][w * 512], phi_src);
      async16(&g_sm[cur ^ 1][w * 512],   g_src);
      phi_src += 4096; g_src += 64;
    }

    const char* phiB = (const char*)&phi_sm[cur][0];
    const char* gB   = (const char*)&g_sm[cur][0];

#pragma unroll
    for (int tt = 0; tt < 2; ++tt){
      __builtin_amdgcn_s_setprio(1);
      f32x16 p;
#pragma unroll
      for (int i = 0; i < 16; ++i) p[i] = 0.f;
#pragma unroll
      for (int ks = 0; ks < 4; ++ks)
        p = __builtin_amdgcn_mfma_f32_32x32x16_bf16(
              *(const bf16x8*)(phiB + tt * 4096 + rb + ((ks * 32 + h * 16) ^ sw)),
              tf[ks], p, 0, 0, 0);
      __builtin_amdgcn_s_setprio(0);

      u32 wpk[4][2];
#pragma unroll
      for (int rq = 0; rq < 4; ++rq){
        const float e0 = fexp2(p[4 * rq + 0]), e1 = fexp2(p[4 * rq + 1]);
        const float e2 = fexp2(p[4 * rq + 2]), e3 = fexp2(p[4 * rq + 3]);
        lacc += (e0 + e1) + (e2 + e3);
        wpk[rq][0] = cvtpk(e0, e1);
        wpk[rq][1] = cvtpk(e2, e3);
      }

      __builtin_amdgcn_s_setprio(1);
#pragma unroll
      for (int par = 0; par < 2; ++par){
        u32 A0 = wpk[2 * par][0],     A1 = wpk[2 * par][1];
        u32 B0 = wpk[2 * par + 1][0], B1 = wpk[2 * par + 1][1];
        asm("v_permlane32_swap_b32 %0, %1" : "+v"(A0), "+v"(B0));
        asm("v_permlane32_swap_b32 %0, %1" : "+v"(A1), "+v"(B1));
        union { u32 u[4]; bf16x8 v; } pw;
        pw.u[0] = A0; pw.u[1] = A1; pw.u[2] = B0; pw.u[3] = B1;
        const int s   = tt * 2 + par;
        const int gof = (s * 32 + h * 16) ^ sw;
        yacc0 = __builtin_amdgcn_mfma_f32_32x32x16_bf16(
                  pw.v, *(const bf16x8*)(gB + rb + gof), yacc0, 0, 0, 0);
        yacc1 = __builtin_amdgcn_mfma_f32_32x32x16_bf16(
                  pw.v, *(const bf16x8*)(gB + 4096 + rb + gof), yacc1, 0, 0, 0);
      }
      __builtin_amdgcn_s_setprio(0);
    }
  }

  // cross-half l combine
  {
    u32 la = __builtin_bit_cast(u32, lacc), lb2 = la;
    asm("v_permlane32_swap_b32 %0, %1" : "+v"(la), "+v"(lb2));
    const float ltot = __builtin_bit_cast(float, la) + __builtin_bit_cast(float, lb2);
    if (l < 32)
      l_part[(size_t)(ms * 4 + b) * NN + n0 + w * 32 + cc] = ltot;
  }

  u16* yp = y_part + ((size_t)(ms * 4 + b) * NN + n0 + w * 32) * 64 + cc;
#pragma unroll
  for (int r = 0; r < 16; ++r){
    const int nl = (r & 3) + 8 * (r >> 2) + 4 * h;
    yp[(size_t)nl * 64]      = f2bf(yacc0[r]);
    yp[(size_t)nl * 64 + 32] = f2bf(yacc1[r]);
  }
}

// ---------------------------------------------------------------------------
// combine (validated): 512 blocks x 32 rows. Sum S bf16 partials, normalize,
// w_out GEMM + bias/ReLU/BN + residual.
// ---------------------------------------------------------------------------
__global__ __launch_bounds__(256) void combine_kernel(
    const u16* __restrict__ y_part, const float* __restrict__ l_part,
    const float* __restrict__ x,
    const float* __restrict__ w_out, const float* __restrict__ b_out,
    const float* __restrict__ bn_gamma, const float* __restrict__ bn_beta,
    float* __restrict__ out, int S)
{
  __shared__ u16 y_sm[32 * 64];       // [row][o] bf16, swizzled
  __shared__ float inv_sm[32];

  const int cb   = blockIdx.x;            // 0..511
  const int b    = cb >> 7;
  const int nin  = (cb & 127) * 32;       // row base within batch
  const int t    = threadIdx.x;
  const int row  = t >> 3;                // 0..31
  const int ch   = t & 7;                 // 16B chunk (8 bf16)

  float s[8] = {0.f,0.f,0.f,0.f,0.f,0.f,0.f,0.f};
  for (int ms = 0; ms < S; ++ms){
    const u16* src = y_part + ((size_t)(ms * 4 + b) * NN + nin + row) * 64 + ch * 8;
    const uint4 v = *(const uint4*)src;
    const u32 ww[4] = {v.x, v.y, v.z, v.w};
#pragma unroll
    for (int i = 0; i < 4; ++i){
      s[2 * i]     += __builtin_bit_cast(float, ww[i] << 16);
      s[2 * i + 1] += __builtin_bit_cast(float, ww[i] & 0xFFFF0000u);
    }
  }
  if (t < 32){
    float ls = 0.f;
    for (int ms = 0; ms < S; ++ms)
      ls += l_part[(size_t)(ms * 4 + b) * NN + nin + t];
    inv_sm[t] = 1.0f / ls;
  }
  __syncthreads();

  {
    const float inv = inv_sm[row];
    uint4 pk;
    pk.x = cvtpk(s[0] * inv, s[1] * inv);
    pk.y = cvtpk(s[2] * inv, s[3] * inv);
    pk.z = cvtpk(s[4] * inv, s[5] * inv);
    pk.w = cvtpk(s[6] * inv, s[7] * inv);
    *(uint4*)((char*)y_sm + ((row * 128 + ch * 16) ^ ((row & 7) << 4))) = pk;
  }
  __syncthreads();

  const int w   = __builtin_amdgcn_readfirstlane(t >> 6);
  const int l   = t & 63;
  const int q   = l & 15;
  const int gg  = l >> 4;
  const int swz = (q & 7) << 4;

  bf16x8 wf[2];
#pragma unroll
  for (int ks = 0; ks < 2; ++ks){
    bf16x8 v;
#pragma unroll
    for (int jj = 0; jj < 8; ++jj)
      v[jj] = (short)f2bf(w_out[(w * 16 + q) * 64 + ks * 32 + gg * 8 + jj]);
    wf[ks] = v;
  }
  f32x4 zacc[2];
  zacc[0] = (f32x4){0.f, 0.f, 0.f, 0.f};
  zacc[1] = (f32x4){0.f, 0.f, 0.f, 0.f};
#pragma unroll
  for (int ks = 0; ks < 2; ++ks)
#pragma unroll
    for (int ns = 0; ns < 2; ++ns){
      const int off = (((ns * 16 + q) * 128) + ks * 64 + gg * 16) ^ swz;
      const bf16x8 yf = *(const bf16x8*)((const char*)y_sm + off);
      zacc[ns] = __builtin_amdgcn_mfma_f32_16x16x32_bf16(wf[ks], yf, zacc[ns], 0, 0, 0);
    }

  float bo[4], sc_[4], bb_[4];
#pragma unroll
  for (int r = 0; r < 4; ++r){
    const int c = w * 16 + gg * 4 + r;
    bo[r]  = b_out[c];
    sc_[r] = bn_gamma[c] * 0.99999500003749969f;  // 1/sqrt(1+1e-5)
    bb_[r] = bn_beta[c];
  }
#pragma unroll
  for (int ns = 0; ns < 2; ++ns)
#pragma unroll
    for (int r = 0; r < 4; ++r){
      const int c  = w * 16 + gg * 4 + r;
      const int ng = nin + ns * 16 + q;
      const size_t idx = ((size_t)(b * 64 + c)) * NN + ng;
      float z = zacc[ns][r] + bo[r];
      z = fmaxf(z, 0.0f);
      z = z * sc_[r] + bb_[r];
      out[idx] = x[idx] + z;
    }
}

// ---------------------------------------------------------------------------
extern "C" void kernel_launch(void* const* d_in, const int* in_sizes, int n_in,
                              void* d_out, int out_size, void* d_ws, size_t ws_size,
                              hipStream_t stream)
{
  (void)in_sizes; (void)n_in; (void)out_size;
  const float* x        = (const float*)d_in[0];
  const float* w_theta  = (const float*)d_in[1];
  const float* b_theta  = (const float*)d_in[2];
  const float* w_phi    = (const float*)d_in[3];
  const float* b_phi    = (const float*)d_in[4];
  const float* w_g      = (const float*)d_in[5];
  const float* b_g      = (const float*)d_in[6];
  const float* w_out    = (const float*)d_in[7];
  const float* b_out    = (const float*)d_in[8];
  const float* bn_gamma = (const float*)d_in[9];
  const float* bn_beta  = (const float*)d_in[10];
  float* out = (float*)d_out;

  u16* theta_t = (u16*)d_ws;                       // 2 MB
  u16* phi_t   = theta_t + (size_t)4 * NN * 64;    // 2 MB
  u16* gbuf    = phi_t   + (size_t)4 * NN * 64;    // 2 MB
  char* after  = (char*)(gbuf + (size_t)4 * NN * 64);
  const size_t used = (size_t)(after - (char*)d_ws);
  const size_t perS = (size_t)4 * NN * 64 * 2 + (size_t)4 * NN * 4; // ~2.16 MB

  // R15 sweep: prefer S=4 (halves y_part round-trip; attn grid 256 = 1 blk/CU)
  int S = 1;
  if      (ws_size >= used + 4 * perS) S = 4;
  else if (ws_size >= used + 2 * perS) S = 2;
  u16*   y_part = (u16*)after;
  float* l_part = (float*)(y_part + (size_t)S * 4 * NN * 64);

  proj_kernel<<<256, 512, 0, stream>>>(x, w_theta, b_theta, w_phi, b_phi,
                                       w_g, b_g, theta_t, phi_t, gbuf);
  if (S == 4)
    attn_kernel<16><<<256, 512, 0, stream>>>(theta_t, phi_t, gbuf, y_part, l_part);
  else if (S == 2)
    attn_kernel<32><<<128, 512, 0, stream>>>(theta_t, phi_t, gbuf, y_part, l_part);
  else
    attn_kernel<64><<<64, 512, 0, stream>>>(theta_t, phi_t, gbuf, y_part, l_part);
  combine_kernel<<<512, 256, 0, stream>>>(y_part, l_part, x, w_out, b_out,
                                          bn_gamma, bn_beta, out, S);
}

// Round 16
// 48.746 us; speedup vs baseline: 6.3256x; 1.0096x over previous
//
#include <hip/hip_runtime.h>

typedef __attribute__((ext_vector_type(4))) float f32x4;
typedef __attribute__((ext_vector_type(16))) float f32x16;
typedef __attribute__((ext_vector_type(8))) short bf16x8;
typedef unsigned short u16;
typedef unsigned int u32;

constexpr int NN = 4096;   // H*W

__device__ __forceinline__ u16 f2bf(float f){
  u32 u = __builtin_bit_cast(u32, f);
  u += 0x7FFFu + ((u >> 16) & 1u);          // round-to-nearest-even
  return (u16)(u >> 16);
}
__device__ __forceinline__ u32 cvtpk(float lo, float hi){
  u32 r;
  asm("v_cvt_pk_bf16_f32 %0, %1, %2" : "=v"(r) : "v"(lo), "v"(hi));
  return r;
}
__device__ __forceinline__ float fexp2(float x){
  float r;
  asm("v_exp_f32 %0, %1" : "=v"(r) : "v"(x));
  return r;
}
__device__ __forceinline__ void async16(void* lds, const void* g){
  __builtin_amdgcn_global_load_lds((const __attribute__((address_space(1))) void*)g,
                                   (__attribute__((address_space(3))) void*)lds,
                                   16, 0, 0);
}

// ---------------------------------------------------------------------------
// proj v8 (validated R14): 256 blocks x 512 threads (8 waves -> 2 waves/SIMD),
// x read ONCE. Wave w computes o in [w*8, w*8+8) for all 3 matrices.
// theta gets *log2e folded in. theta_t/phi_t: [b][n][o] bf16; g: [b][o][n].
// ---------------------------------------------------------------------------
__global__ __launch_bounds__(512) void proj_kernel(
    const float* __restrict__ x,
    const float* __restrict__ wth, const float* __restrict__ bth,
    const float* __restrict__ wph, const float* __restrict__ bph,
    const float* __restrict__ wg,  const float* __restrict__ bg,
    u16* __restrict__ theta_t, u16* __restrict__ phi_t, u16* __restrict__ gbuf)
{
  __shared__ float Wsm[3 * 4096];   // 48 KB
  __shared__ float Bsm[3 * 64];

  const int t = threadIdx.x;
#pragma unroll
  for (int i = 0; i < 6; ++i){
    const int idx = i * 512 + t;             // 0..3071 float4s
    const float4 v = (idx < 1024) ? ((const float4*)wth)[idx]
                   : (idx < 2048) ? ((const float4*)wph)[idx - 1024]
                                  : ((const float4*)wg)[idx - 2048];
    ((float4*)Wsm)[idx] = v;
  }
  if (t < 192) Bsm[t] = (t < 64) ? bth[t] : (t < 128) ? bph[t - 64] : bg[t - 128];

  const int b = blockIdx.x >> 6;
  const int n = (blockIdx.x & 63) * 64 + (t & 63);
  const int w = __builtin_amdgcn_readfirstlane(t >> 6);   // 0..7
  const int ob = w * 8;

  const float* xb = x + ((size_t)b * 64) * NN + n;
  float xr[64];
#pragma unroll
  for (int c = 0; c < 64; ++c) xr[c] = xb[(size_t)c * NN];

  __syncthreads();

  for (int mat = 0; mat < 3; ++mat){
    const float* Wm = Wsm + mat * 4096 + ob * 64;
    float acc[8];
#pragma unroll
    for (int oo = 0; oo < 8; ++oo) acc[oo] = Bsm[mat * 64 + ob + oo];
#pragma unroll
    for (int c4 = 0; c4 < 16; ++c4)
#pragma unroll
      for (int oo = 0; oo < 8; ++oo){
        const float4 wv = *(const float4*)&Wm[oo * 64 + c4 * 4];  // wave-broadcast
        acc[oo] = fmaf(wv.x, xr[4 * c4],     acc[oo]);
        acc[oo] = fmaf(wv.y, xr[4 * c4 + 1], acc[oo]);
        acc[oo] = fmaf(wv.z, xr[4 * c4 + 2], acc[oo]);
        acc[oo] = fmaf(wv.w, xr[4 * c4 + 3], acc[oo]);
      }
    if (mat == 0){
#pragma unroll
      for (int oo = 0; oo < 8; ++oo) acc[oo] *= 1.44269504088896340736f;
    }
    if (mat < 2){
      uint4 pk;
      pk.x = cvtpk(acc[0], acc[1]); pk.y = cvtpk(acc[2], acc[3]);
      pk.z = cvtpk(acc[4], acc[5]); pk.w = cvtpk(acc[6], acc[7]);
      u16* base = (mat == 0) ? theta_t : phi_t;
      *(uint4*)(base + ((size_t)(b * NN + n)) * 64 + ob) = pk;
    } else {
#pragma unroll
      for (int oo = 0; oo < 8; ++oo)
        gbuf[((size_t)(b * 64 + ob + oo)) * NN + n] = f2bf(acc[oo]);
    }
  }
}

// ---------------------------------------------------------------------------
// attn v11: 3-buffer staging, counted vmcnt(2) (2-tile prefetch distance),
// still ONE stage (2 loads) per barrier — the validated quantum. Raw
// s_barrier + compiler fences (syncthreads would re-drain vmcnt to 0).
// 32x32x16 MFMA flash, BM=256 (8 waves x 32 rows), m-split S, XCD swizzle.
// LDS 48KB -> 2 blocks/CU. Pair-staging (4 loads/stage) remains BANNED.
// ---------------------------------------------------------------------------
template<int TPB>
__global__ __launch_bounds__(512, 4) void attn_kernel(
    const u16* __restrict__ theta_t, const u16* __restrict__ phi_t,
    const u16* __restrict__ gbuf,
    u16* __restrict__ y_part, float* __restrict__ l_part)
{
  __shared__ u16 phi_sm[3][64 * 64];  // [buf][m_loc*64+o], XOR-swizzled
  __shared__ u16 g_sm[3][64 * 64];    // [buf][o*64+m_loc], XOR-swizzled

  const int j   = blockIdx.x;
  const int cpx = gridDim.x >> 3;
  const int lb  = (j & 7) * cpx + (j >> 3);   // bijective (grid % 8 == 0)

  const int ms  = lb >> 6;            // m-split index
  const int pr  = lb & 63;
  const int b   = pr >> 4;
  const int n0  = (pr & 15) * 256;

  const int tid = threadIdx.x;
  const int w   = __builtin_amdgcn_readfirstlane(tid >> 6); // 0..7
  const int l   = tid & 63;
  const int cc  = l & 31;
  const int h   = l >> 5;
  const int sw  = (cc & 7) << 4;
  const int rb  = cc * 128;

  const u16* thb = theta_t + (size_t)b * NN * 64;

  bf16x8 tf[4];
#pragma unroll
  for (int ks = 0; ks < 4; ++ks)
    tf[ks] = *(const bf16x8*)(thb + (size_t)(n0 + w * 32 + cc) * 64 + ks * 16 + h * 8);

  const int m0 = ms * TPB;
  const int r8 = l >> 3;
  const int c8 = l & 7;
  const u16* phi_src = phi_t + (size_t)b * NN * 64
                     + (size_t)(m0 * 64 + w * 8 + r8) * 64 + (c8 ^ r8) * 8;
  const u16* g_src   = gbuf + (size_t)b * 64 * NN
                     + (size_t)(w * 8 + r8) * NN + m0 * 64 + (c8 ^ r8) * 8;

  f32x16 yacc0, yacc1;
#pragma unroll
  for (int i = 0; i < 16; ++i){ yacc0[i] = 0.f; yacc1[i] = 0.f; }
  float lacc = 0.f;

  // prologue: stage tiles 0 and 1 (2 loads each — validated quantum/stage)
  async16(&phi_sm[0][w * 512], phi_src);
  async16(&g_sm[0][w * 512],   g_src);
  phi_src += 4096; g_src += 64;
  async16(&phi_sm[1][w * 512], phi_src);
  async16(&g_sm[1][w * 512],   g_src);
  phi_src += 4096; g_src += 64;

#pragma unroll
  for (int it = 0; it < TPB; ++it){
    const int cur = it % 3;
    // counted wait: tile `it`'s 2 loads are the OLDEST outstanding; the
    // (≤2) newer ones (tile it+1) may stay in flight across the barrier.
    if (it < TPB - 1)
      asm volatile("s_waitcnt vmcnt(2)" ::: "memory");
    else
      asm volatile("s_waitcnt vmcnt(0)" ::: "memory");
    asm volatile("" ::: "memory");
    __builtin_amdgcn_s_barrier();
    asm volatile("" ::: "memory");
    if (it + 2 < TPB){
      // stage tile it+2 into buffer (it+2)%3 == (it-1)%3, whose tile it-1
      // was consumed before barrier(it) by every wave (R12 safety argument).
      async16(&phi_sm[(it + 2) % 3][w * 512], phi_src);
      async16(&g_sm[(it + 2) % 3][w * 512],   g_src);
      phi_src += 4096; g_src += 64;
    }

    const char* phiB = (const char*)&phi_sm[cur][0];
    const char* gB   = (const char*)&g_sm[cur][0];

#pragma unroll
    for (int tt = 0; tt < 2; ++tt){
      __builtin_amdgcn_s_setprio(1);
      f32x16 p;
#pragma unroll
      for (int i = 0; i < 16; ++i) p[i] = 0.f;
#pragma unroll
      for (int ks = 0; ks < 4; ++ks)
        p = __builtin_amdgcn_mfma_f32_32x32x16_bf16(
              *(const bf16x8*)(phiB + tt * 4096 + rb + ((ks * 32 + h * 16) ^ sw)),
              tf[ks], p, 0, 0, 0);
      __builtin_amdgcn_s_setprio(0);

      u32 wpk[4][2];
#pragma unroll
      for (int rq = 0; rq < 4; ++rq){
        const float e0 = fexp2(p[4 * rq + 0]), e1 = fexp2(p[4 * rq + 1]);
        const float e2 = fexp2(p[4 * rq + 2]), e3 = fexp2(p[4 * rq + 3]);
        lacc += (e0 + e1) + (e2 + e3);
        wpk[rq][0] = cvtpk(e0, e1);
        wpk[rq][1] = cvtpk(e2, e3);
      }

      __builtin_amdgcn_s_setprio(1);
#pragma unroll
      for (int par = 0; par < 2; ++par){
        u32 A0 = wpk[2 * par][0],     A1 = wpk[2 * par][1];
        u32 B0 = wpk[2 * par + 1][0], B1 = wpk[2 * par + 1][1];
        asm("v_permlane32_swap_b32 %0, %1" : "+v"(A0), "+v"(B0));
        asm("v_permlane32_swap_b32 %0, %1" : "+v"(A1), "+v"(B1));
        union { u32 u[4]; bf16x8 v; } pw;
        pw.u[0] = A0; pw.u[1] = A1; pw.u[2] = B0; pw.u[3] = B1;
        const int s   = tt * 2 + par;
        const int gof = (s * 32 + h * 16) ^ sw;
        yacc0 = __builtin_amdgcn_mfma_f32_32x32x16_bf16(
                  pw.v, *(const bf16x8*)(gB + rb + gof), yacc0, 0, 0, 0);
        yacc1 = __builtin_amdgcn_mfma_f32_32x32x16_bf16(
                  pw.v, *(const bf16x8*)(gB + 4096 + rb + gof), yacc1, 0, 0, 0);
      }
      __builtin_amdgcn_s_setprio(0);
    }
  }

  // cross-half l combine
  {
    u32 la = __builtin_bit_cast(u32, lacc), lb2 = la;
    asm("v_permlane32_swap_b32 %0, %1" : "+v"(la), "+v"(lb2));
    const float ltot = __builtin_bit_cast(float, la) + __builtin_bit_cast(float, lb2);
    if (l < 32)
      l_part[(size_t)(ms * 4 + b) * NN + n0 + w * 32 + cc] = ltot;
  }

  u16* yp = y_part + ((size_t)(ms * 4 + b) * NN + n0 + w * 32) * 64 + cc;
#pragma unroll
  for (int r = 0; r < 16; ++r){
    const int nl = (r & 3) + 8 * (r >> 2) + 4 * h;
    yp[(size_t)nl * 64]      = f2bf(yacc0[r]);
    yp[(size_t)nl * 64 + 32] = f2bf(yacc1[r]);
  }
}

// ---------------------------------------------------------------------------
// combine (validated): 512 blocks x 32 rows. Sum S bf16 partials, normalize,
// w_out GEMM + bias/ReLU/BN + residual.
// ---------------------------------------------------------------------------
__global__ __launch_bounds__(256) void combine_kernel(
    const u16* __restrict__ y_part, const float* __restrict__ l_part,
    const float* __restrict__ x,
    const float* __restrict__ w_out, const float* __restrict__ b_out,
    const float* __restrict__ bn_gamma, const float* __restrict__ bn_beta,
    float* __restrict__ out, int S)
{
  __shared__ u16 y_sm[32 * 64];       // [row][o] bf16, swizzled
  __shared__ float inv_sm[32];

  const int cb   = blockIdx.x;            // 0..511
  const int b    = cb >> 7;
  const int nin  = (cb & 127) * 32;       // row base within batch
  const int t    = threadIdx.x;
  const int row  = t >> 3;                // 0..31
  const int ch   = t & 7;                 // 16B chunk (8 bf16)

  float s[8] = {0.f,0.f,0.f,0.f,0.f,0.f,0.f,0.f};
  for (int ms = 0; ms < S; ++ms){
    const u16* src = y_part + ((size_t)(ms * 4 + b) * NN + nin + row) * 64 + ch * 8;
    const uint4 v = *(const uint4*)src;
    const u32 ww[4] = {v.x, v.y, v.z, v.w};
#pragma unroll
    for (int i = 0; i < 4; ++i){
      s[2 * i]     += __builtin_bit_cast(float, ww[i] << 16);
      s[2 * i + 1] += __builtin_bit_cast(float, ww[i] & 0xFFFF0000u);
    }
  }
  if (t < 32){
    float ls = 0.f;
    for (int ms = 0; ms < S; ++ms)
      ls += l_part[(size_t)(ms * 4 + b) * NN + nin + t];
    inv_sm[t] = 1.0f / ls;
  }
  __syncthreads();

  {
    const float inv = inv_sm[row];
    uint4 pk;
    pk.x = cvtpk(s[0] * inv, s[1] * inv);
    pk.y = cvtpk(s[2] * inv, s[3] * inv);
    pk.z = cvtpk(s[4] * inv, s[5] * inv);
    pk.w = cvtpk(s[6] * inv, s[7] * inv);
    *(uint4*)((char*)y_sm + ((row * 128 + ch * 16) ^ ((row & 7) << 4))) = pk;
  }
  __syncthreads();

  const int w   = __builtin_amdgcn_readfirstlane(t >> 6);
  const int l   = t & 63;
  const int q   = l & 15;
  const int gg  = l >> 4;
  const int swz = (q & 7) << 4;

  bf16x8 wf[2];
#pragma unroll
  for (int ks = 0; ks < 2; ++ks){
    bf16x8 v;
#pragma unroll
    for (int jj = 0; jj < 8; ++jj)
      v[jj] = (short)f2bf(w_out[(w * 16 + q) * 64 + ks * 32 + gg * 8 + jj]);
    wf[ks] = v;
  }
  f32x4 zacc[2];
  zacc[0] = (f32x4){0.f, 0.f, 0.f, 0.f};
  zacc[1] = (f32x4){0.f, 0.f, 0.f, 0.f};
#pragma unroll
  for (int ks = 0; ks < 2; ++ks)
#pragma unroll
    for (int ns = 0; ns < 2; ++ns){
      const int off = (((ns * 16 + q) * 128) + ks * 64 + gg * 16) ^ swz;
      const bf16x8 yf = *(const bf16x8*)((const char*)y_sm + off);
      zacc[ns] = __builtin_amdgcn_mfma_f32_16x16x32_bf16(wf[ks], yf, zacc[ns], 0, 0, 0);
    }

  float bo[4], sc_[4], bb_[4];
#pragma unroll
  for (int r = 0; r < 4; ++r){
    const int c = w * 16 + gg * 4 + r;
    bo[r]  = b_out[c];
    sc_[r] = bn_gamma[c] * 0.99999500003749969f;  // 1/sqrt(1+1e-5)
    bb_[r] = bn_beta[c];
  }
#pragma unroll
  for (int ns = 0; ns < 2; ++ns)
#pragma unroll
    for (int r = 0; r < 4; ++r){
      const int c  = w * 16 + gg * 4 + r;
      const int ng = nin + ns * 16 + q;
      const size_t idx = ((size_t)(b * 64 + c)) * NN + ng;
      float z = zacc[ns][r] + bo[r];
      z = fmaxf(z, 0.0f);
      z = z * sc_[r] + bb_[r];
      out[idx] = x[idx] + z;
    }
}

// ---------------------------------------------------------------------------
extern "C" void kernel_launch(void* const* d_in, const int* in_sizes, int n_in,
                              void* d_out, int out_size, void* d_ws, size_t ws_size,
                              hipStream_t stream)
{
  (void)in_sizes; (void)n_in; (void)out_size;
  const float* x        = (const float*)d_in[0];
  const float* w_theta  = (const float*)d_in[1];
  const float* b_theta  = (const float*)d_in[2];
  const float* w_phi    = (const float*)d_in[3];
  const float* b_phi    = (const float*)d_in[4];
  const float* w_g      = (const float*)d_in[5];
  const float* b_g      = (const float*)d_in[6];
  const float* w_out    = (const float*)d_in[7];
  const float* b_out    = (const float*)d_in[8];
  const float* bn_gamma = (const float*)d_in[9];
  const float* bn_beta  = (const float*)d_in[10];
  float* out = (float*)d_out;

  u16* theta_t = (u16*)d_ws;                       // 2 MB
  u16* phi_t   = theta_t + (size_t)4 * NN * 64;    // 2 MB
  u16* gbuf    = phi_t   + (size_t)4 * NN * 64;    // 2 MB
  char* after  = (char*)(gbuf + (size_t)4 * NN * 64);
  const size_t used = (size_t)(after - (char*)d_ws);
  const size_t perS = (size_t)4 * NN * 64 * 2 + (size_t)4 * NN * 4; // ~2.16 MB

  int S = 1;
  if      (ws_size >= used + 8 * perS) S = 8;
  else if (ws_size >= used + 4 * perS) S = 4;
  else if (ws_size >= used + 2 * perS) S = 2;
  u16*   y_part = (u16*)after;
  float* l_part = (float*)(y_part + (size_t)S * 4 * NN * 64);

  proj_kernel<<<256, 512, 0, stream>>>(x, w_theta, b_theta, w_phi, b_phi,
                                       w_g, b_g, theta_t, phi_t, gbuf);
  if (S == 8)
    attn_kernel<8><<<512, 512, 0, stream>>>(theta_t, phi_t, gbuf, y_part, l_part);
  else if (S == 4)
    attn_kernel<16><<<256, 512, 0, stream>>>(theta_t, phi_t, gbuf, y_part, l_part);
  else if (S == 2)
    attn_kernel<32><<<128, 512, 0, stream>>>(theta_t, phi_t, gbuf, y_part, l_part);
  else
    attn_kernel<64><<<64, 512, 0, stream>>>(theta_t, phi_t, gbuf, y_part, l_part);
  combine_kernel<<<512, 256, 0, stream>>>(y_part, l_part, x, w_out, b_out,
                                          bn_gamma, bn_beta, out, S);
}

// Round 17
// 47.513 us; speedup vs baseline: 6.4898x; 1.0260x over previous
//
#include <hip/hip_runtime.h>

typedef __attribute__((ext_vector_type(4))) float f32x4;
typedef __attribute__((ext_vector_type(16))) float f32x16;
typedef __attribute__((ext_vector_type(8))) short bf16x8;
typedef unsigned short u16;
typedef unsigned int u32;

constexpr int NN = 4096;   // H*W

__device__ __forceinline__ u16 f2bf(float f){
  u32 u = __builtin_bit_cast(u32, f);
  u += 0x7FFFu + ((u >> 16) & 1u);          // round-to-nearest-even
  return (u16)(u >> 16);
}
__device__ __forceinline__ u32 cvtpk(float lo, float hi){
  u32 r;
  asm("v_cvt_pk_bf16_f32 %0, %1, %2" : "=v"(r) : "v"(lo), "v"(hi));
  return r;
}
__device__ __forceinline__ float fexp2(float x){
  float r;
  asm("v_exp_f32 %0, %1" : "=v"(r) : "v"(x));
  return r;
}
__device__ __forceinline__ void async16(void* lds, const void* g){
  __builtin_amdgcn_global_load_lds((const __attribute__((address_space(1))) void*)g,
                                   (__attribute__((address_space(3))) void*)lds,
                                   16, 0, 0);
}

// ---------------------------------------------------------------------------
// proj v8 (validated R14): 256 blocks x 512 threads (8 waves -> 2 waves/SIMD),
// x read ONCE. Wave w computes o in [w*8, w*8+8) for all 3 matrices.
// theta gets *log2e folded in. theta_t/phi_t: [b][n][o] bf16; g: [b][o][n].
// ---------------------------------------------------------------------------
__global__ __launch_bounds__(512) void proj_kernel(
    const float* __restrict__ x,
    const float* __restrict__ wth, const float* __restrict__ bth,
    const float* __restrict__ wph, const float* __restrict__ bph,
    const float* __restrict__ wg,  const float* __restrict__ bg,
    u16* __restrict__ theta_t, u16* __restrict__ phi_t, u16* __restrict__ gbuf)
{
  __shared__ float Wsm[3 * 4096];   // 48 KB
  __shared__ float Bsm[3 * 64];

  const int t = threadIdx.x;
#pragma unroll
  for (int i = 0; i < 6; ++i){
    const int idx = i * 512 + t;             // 0..3071 float4s
    const float4 v = (idx < 1024) ? ((const float4*)wth)[idx]
                   : (idx < 2048) ? ((const float4*)wph)[idx - 1024]
                                  : ((const float4*)wg)[idx - 2048];
    ((float4*)Wsm)[idx] = v;
  }
  if (t < 192) Bsm[t] = (t < 64) ? bth[t] : (t < 128) ? bph[t - 64] : bg[t - 128];

  const int b = blockIdx.x >> 6;
  const int n = (blockIdx.x & 63) * 64 + (t & 63);
  const int w = __builtin_amdgcn_readfirstlane(t >> 6);   // 0..7
  const int ob = w * 8;

  const float* xb = x + ((size_t)b * 64) * NN + n;
  float xr[64];
#pragma unroll
  for (int c = 0; c < 64; ++c) xr[c] = xb[(size_t)c * NN];

  __syncthreads();

  for (int mat = 0; mat < 3; ++mat){
    const float* Wm = Wsm + mat * 4096 + ob * 64;
    float acc[8];
#pragma unroll
    for (int oo = 0; oo < 8; ++oo) acc[oo] = Bsm[mat * 64 + ob + oo];
#pragma unroll
    for (int c4 = 0; c4 < 16; ++c4)
#pragma unroll
      for (int oo = 0; oo < 8; ++oo){
        const float4 wv = *(const float4*)&Wm[oo * 64 + c4 * 4];  // wave-broadcast
        acc[oo] = fmaf(wv.x, xr[4 * c4],     acc[oo]);
        acc[oo] = fmaf(wv.y, xr[4 * c4 + 1], acc[oo]);
        acc[oo] = fmaf(wv.z, xr[4 * c4 + 2], acc[oo]);
        acc[oo] = fmaf(wv.w, xr[4 * c4 + 3], acc[oo]);
      }
    if (mat == 0){
#pragma unroll
      for (int oo = 0; oo < 8; ++oo) acc[oo] *= 1.44269504088896340736f;
    }
    if (mat < 2){
      uint4 pk;
      pk.x = cvtpk(acc[0], acc[1]); pk.y = cvtpk(acc[2], acc[3]);
      pk.z = cvtpk(acc[4], acc[5]); pk.w = cvtpk(acc[6], acc[7]);
      u16* base = (mat == 0) ? theta_t : phi_t;
      *(uint4*)(base + ((size_t)(b * NN + n)) * 64 + ob) = pk;
    } else {
#pragma unroll
      for (int oo = 0; oo < 8; ++oo)
        gbuf[((size_t)(b * 64 + ob + oo)) * NN + n] = f2bf(acc[oo]);
    }
  }
}

// ---------------------------------------------------------------------------
// attn v12: BM=512 — 2 n-tiles per wave, halving LDS bytes per FLOP (each
// phi/g fragment feeds 2 MFMAs). R16's validated 3-buffer counted-vmcnt
// schedule verbatim (2 loads/stage/wave quantum; pair-staging stays BANNED).
// grid = 32*S (1 block/CU at S=8), 512 threads.
// ---------------------------------------------------------------------------
template<int TPB>
__global__ __launch_bounds__(512, 2) void attn_kernel(
    const u16* __restrict__ theta_t, const u16* __restrict__ phi_t,
    const u16* __restrict__ gbuf,
    u16* __restrict__ y_part, float* __restrict__ l_part)
{
  __shared__ u16 phi_sm[3][64 * 64];  // [buf][m_loc*64+o], XOR-swizzled
  __shared__ u16 g_sm[3][64 * 64];    // [buf][o*64+m_loc], XOR-swizzled

  const int j   = blockIdx.x;
  const int cpx = gridDim.x >> 3;
  const int lb  = (j & 7) * cpx + (j >> 3);   // bijective (grid % 8 == 0)

  const int ms  = lb >> 5;            // m-split index
  const int pr  = lb & 31;            // batch*8 + n-chunk
  const int b   = pr >> 3;
  const int n0  = (pr & 7) * 512;

  const int tid = threadIdx.x;
  const int w   = __builtin_amdgcn_readfirstlane(tid >> 6); // 0..7
  const int l   = tid & 63;
  const int cc  = l & 31;
  const int h   = l >> 5;
  const int sw  = (cc & 7) << 4;
  const int rb  = cc * 128;

  const u16* thb = theta_t + (size_t)b * NN * 64;

  // theta fragments for the wave's TWO 32-row n-tiles
  bf16x8 tf0[4], tf1[4];
#pragma unroll
  for (int ks = 0; ks < 4; ++ks){
    tf0[ks] = *(const bf16x8*)(thb + (size_t)(n0 + w * 64 + cc) * 64 + ks * 16 + h * 8);
    tf1[ks] = *(const bf16x8*)(thb + (size_t)(n0 + w * 64 + 32 + cc) * 64 + ks * 16 + h * 8);
  }

  const int m0 = ms * TPB;
  const int r8 = l >> 3;
  const int c8 = l & 7;
  const u16* phi_src = phi_t + (size_t)b * NN * 64
                     + (size_t)(m0 * 64 + w * 8 + r8) * 64 + (c8 ^ r8) * 8;
  const u16* g_src   = gbuf + (size_t)b * 64 * NN
                     + (size_t)(w * 8 + r8) * NN + m0 * 64 + (c8 ^ r8) * 8;

  f32x16 yacc00, yacc01, yacc10, yacc11;   // [nt][o-half]
#pragma unroll
  for (int i = 0; i < 16; ++i){
    yacc00[i] = 0.f; yacc01[i] = 0.f; yacc10[i] = 0.f; yacc11[i] = 0.f;
  }
  float lacc0 = 0.f, lacc1 = 0.f;

  // prologue: stage tiles 0 and 1 (2 loads each — validated quantum/stage)
  async16(&phi_sm[0][w * 512], phi_src);
  async16(&g_sm[0][w * 512],   g_src);
  phi_src += 4096; g_src += 64;
  async16(&phi_sm[1][w * 512], phi_src);
  async16(&g_sm[1][w * 512],   g_src);
  phi_src += 4096; g_src += 64;

#pragma unroll
  for (int it = 0; it < TPB; ++it){
    const int cur = it % 3;
    if (it < TPB - 1)
      asm volatile("s_waitcnt vmcnt(2)" ::: "memory");
    else
      asm volatile("s_waitcnt vmcnt(0)" ::: "memory");
    asm volatile("" ::: "memory");
    __builtin_amdgcn_s_barrier();
    asm volatile("" ::: "memory");
    if (it + 2 < TPB){
      async16(&phi_sm[(it + 2) % 3][w * 512], phi_src);
      async16(&g_sm[(it + 2) % 3][w * 512],   g_src);
      phi_src += 4096; g_src += 64;
    }

    const char* phiB = (const char*)&phi_sm[cur][0];
    const char* gB   = (const char*)&g_sm[cur][0];

#pragma unroll
    for (int tt = 0; tt < 2; ++tt){
      // QK^T: each phi fragment feeds BOTH n-tiles
      __builtin_amdgcn_s_setprio(1);
      f32x16 p0, p1;
#pragma unroll
      for (int i = 0; i < 16; ++i){ p0[i] = 0.f; p1[i] = 0.f; }
#pragma unroll
      for (int ks = 0; ks < 4; ++ks){
        const bf16x8 pf = *(const bf16x8*)(phiB + tt * 4096 + rb + ((ks * 32 + h * 16) ^ sw));
        p0 = __builtin_amdgcn_mfma_f32_32x32x16_bf16(pf, tf0[ks], p0, 0, 0, 0);
        p1 = __builtin_amdgcn_mfma_f32_32x32x16_bf16(pf, tf1[ks], p1, 0, 0, 0);
      }
      __builtin_amdgcn_s_setprio(0);

      // fixed-base softmax for both n-tiles
      u32 wpk0[4][2], wpk1[4][2];
#pragma unroll
      for (int rq = 0; rq < 4; ++rq){
        float e0 = fexp2(p0[4 * rq + 0]), e1 = fexp2(p0[4 * rq + 1]);
        float e2 = fexp2(p0[4 * rq + 2]), e3 = fexp2(p0[4 * rq + 3]);
        lacc0 += (e0 + e1) + (e2 + e3);
        wpk0[rq][0] = cvtpk(e0, e1);
        wpk0[rq][1] = cvtpk(e2, e3);
        e0 = fexp2(p1[4 * rq + 0]); e1 = fexp2(p1[4 * rq + 1]);
        e2 = fexp2(p1[4 * rq + 2]); e3 = fexp2(p1[4 * rq + 3]);
        lacc1 += (e0 + e1) + (e2 + e3);
        wpk1[rq][0] = cvtpk(e0, e1);
        wpk1[rq][1] = cvtpk(e2, e3);
      }

      // PV: each g fragment feeds BOTH n-tiles
      __builtin_amdgcn_s_setprio(1);
#pragma unroll
      for (int par = 0; par < 2; ++par){
        u32 A0 = wpk0[2 * par][0],     A1 = wpk0[2 * par][1];
        u32 B0 = wpk0[2 * par + 1][0], B1 = wpk0[2 * par + 1][1];
        asm("v_permlane32_swap_b32 %0, %1" : "+v"(A0), "+v"(B0));
        asm("v_permlane32_swap_b32 %0, %1" : "+v"(A1), "+v"(B1));
        union { u32 u[4]; bf16x8 v; } pw0;
        pw0.u[0] = A0; pw0.u[1] = A1; pw0.u[2] = B0; pw0.u[3] = B1;
        u32 C0 = wpk1[2 * par][0],     C1 = wpk1[2 * par][1];
        u32 D0 = wpk1[2 * par + 1][0], D1 = wpk1[2 * par + 1][1];
        asm("v_permlane32_swap_b32 %0, %1" : "+v"(C0), "+v"(D0));
        asm("v_permlane32_swap_b32 %0, %1" : "+v"(C1), "+v"(D1));
        union { u32 u[4]; bf16x8 v; } pw1;
        pw1.u[0] = C0; pw1.u[1] = C1; pw1.u[2] = D0; pw1.u[3] = D1;

        const int s   = tt * 2 + par;
        const int gof = (s * 32 + h * 16) ^ sw;
        const bf16x8 g0 = *(const bf16x8*)(gB + rb + gof);
        const bf16x8 g1 = *(const bf16x8*)(gB + 4096 + rb + gof);
        yacc00 = __builtin_amdgcn_mfma_f32_32x32x16_bf16(pw0.v, g0, yacc00, 0, 0, 0);
        yacc01 = __builtin_amdgcn_mfma_f32_32x32x16_bf16(pw0.v, g1, yacc01, 0, 0, 0);
        yacc10 = __builtin_amdgcn_mfma_f32_32x32x16_bf16(pw1.v, g0, yacc10, 0, 0, 0);
        yacc11 = __builtin_amdgcn_mfma_f32_32x32x16_bf16(pw1.v, g1, yacc11, 0, 0, 0);
      }
      __builtin_amdgcn_s_setprio(0);
    }
  }

  // cross-half l combine + partial writes, per n-tile
  {
    u32 la = __builtin_bit_cast(u32, lacc0), lb2 = la;
    asm("v_permlane32_swap_b32 %0, %1" : "+v"(la), "+v"(lb2));
    const float lt0 = __builtin_bit_cast(float, la) + __builtin_bit_cast(float, lb2);
    u32 lc = __builtin_bit_cast(u32, lacc1), ld = lc;
    asm("v_permlane32_swap_b32 %0, %1" : "+v"(lc), "+v"(ld));
    const float lt1 = __builtin_bit_cast(float, lc) + __builtin_bit_cast(float, ld);
    if (l < 32){
      l_part[(size_t)(ms * 4 + b) * NN + n0 + w * 64 + cc]      = lt0;
      l_part[(size_t)(ms * 4 + b) * NN + n0 + w * 64 + 32 + cc] = lt1;
    }
  }

  u16* yp0 = y_part + ((size_t)(ms * 4 + b) * NN + n0 + w * 64) * 64 + cc;
  u16* yp1 = y_part + ((size_t)(ms * 4 + b) * NN + n0 + w * 64 + 32) * 64 + cc;
#pragma unroll
  for (int r = 0; r < 16; ++r){
    const int nl = (r & 3) + 8 * (r >> 2) + 4 * h;
    yp0[(size_t)nl * 64]      = f2bf(yacc00[r]);
    yp0[(size_t)nl * 64 + 32] = f2bf(yacc01[r]);
    yp1[(size_t)nl * 64]      = f2bf(yacc10[r]);
    yp1[(size_t)nl * 64 + 32] = f2bf(yacc11[r]);
  }
}

// ---------------------------------------------------------------------------
// combine (validated): 512 blocks x 32 rows. Sum S bf16 partials, normalize,
// w_out GEMM + bias/ReLU/BN + residual.
// ---------------------------------------------------------------------------
__global__ __launch_bounds__(256) void combine_kernel(
    const u16* __restrict__ y_part, const float* __restrict__ l_part,
    const float* __restrict__ x,
    const float* __restrict__ w_out, const float* __restrict__ b_out,
    const float* __restrict__ bn_gamma, const float* __restrict__ bn_beta,
    float* __restrict__ out, int S)
{
  __shared__ u16 y_sm[32 * 64];       // [row][o] bf16, swizzled
  __shared__ float inv_sm[32];

  const int cb   = blockIdx.x;            // 0..511
  const int b    = cb >> 7;
  const int nin  = (cb & 127) * 32;       // row base within batch
  const int t    = threadIdx.x;
  const int row  = t >> 3;                // 0..31
  const int ch   = t & 7;                 // 16B chunk (8 bf16)

  float s[8] = {0.f,0.f,0.f,0.f,0.f,0.f,0.f,0.f};
  for (int ms = 0; ms < S; ++ms){
    const u16* src = y_part + ((size_t)(ms * 4 + b) * NN + nin + row) * 64 + ch * 8;
    const uint4 v = *(const uint4*)src;
    const u32 ww[4] = {v.x, v.y, v.z, v.w};
#pragma unroll
    for (int i = 0; i < 4; ++i){
      s[2 * i]     += __builtin_bit_cast(float, ww[i] << 16);
      s[2 * i + 1] += __builtin_bit_cast(float, ww[i] & 0xFFFF0000u);
    }
  }
  if (t < 32){
    float ls = 0.f;
    for (int ms = 0; ms < S; ++ms)
      ls += l_part[(size_t)(ms * 4 + b) * NN + nin + t];
    inv_sm[t] = 1.0f / ls;
  }
  __syncthreads();

  {
    const float inv = inv_sm[row];
    uint4 pk;
    pk.x = cvtpk(s[0] * inv, s[1] * inv);
    pk.y = cvtpk(s[2] * inv, s[3] * inv);
    pk.z = cvtpk(s[4] * inv, s[5] * inv);
    pk.w = cvtpk(s[6] * inv, s[7] * inv);
    *(uint4*)((char*)y_sm + ((row * 128 + ch * 16) ^ ((row & 7) << 4))) = pk;
  }
  __syncthreads();

  const int w   = __builtin_amdgcn_readfirstlane(t >> 6);
  const int l   = t & 63;
  const int q   = l & 15;
  const int gg  = l >> 4;
  const int swz = (q & 7) << 4;

  bf16x8 wf[2];
#pragma unroll
  for (int ks = 0; ks < 2; ++ks){
    bf16x8 v;
#pragma unroll
    for (int jj = 0; jj < 8; ++jj)
      v[jj] = (short)f2bf(w_out[(w * 16 + q) * 64 + ks * 32 + gg * 8 + jj]);
    wf[ks] = v;
  }
  f32x4 zacc[2];
  zacc[0] = (f32x4){0.f, 0.f, 0.f, 0.f};
  zacc[1] = (f32x4){0.f, 0.f, 0.f, 0.f};
#pragma unroll
  for (int ks = 0; ks < 2; ++ks)
#pragma unroll
    for (int ns = 0; ns < 2; ++ns){
      const int off = (((ns * 16 + q) * 128) + ks * 64 + gg * 16) ^ swz;
      const bf16x8 yf = *(const bf16x8*)((const char*)y_sm + off);
      zacc[ns] = __builtin_amdgcn_mfma_f32_16x16x32_bf16(wf[ks], yf, zacc[ns], 0, 0, 0);
    }

  float bo[4], sc_[4], bb_[4];
#pragma unroll
  for (int r = 0; r < 4; ++r){
    const int c = w * 16 + gg * 4 + r;
    bo[r]  = b_out[c];
    sc_[r] = bn_gamma[c] * 0.99999500003749969f;  // 1/sqrt(1+1e-5)
    bb_[r] = bn_beta[c];
  }
#pragma unroll
  for (int ns = 0; ns < 2; ++ns)
#pragma unroll
    for (int r = 0; r < 4; ++r){
      const int c  = w * 16 + gg * 4 + r;
      const int ng = nin + ns * 16 + q;
      const size_t idx = ((size_t)(b * 64 + c)) * NN + ng;
      float z = zacc[ns][r] + bo[r];
      z = fmaxf(z, 0.0f);
      z = z * sc_[r] + bb_[r];
      out[idx] = x[idx] + z;
    }
}

// ---------------------------------------------------------------------------
extern "C" void kernel_launch(void* const* d_in, const int* in_sizes, int n_in,
                              void* d_out, int out_size, void* d_ws, size_t ws_size,
                              hipStream_t stream)
{
  (void)in_sizes; (void)n_in; (void)out_size;
  const float* x        = (const float*)d_in[0];
  const float* w_theta  = (const float*)d_in[1];
  const float* b_theta  = (const float*)d_in[2];
  const float* w_phi    = (const float*)d_in[3];
  const float* b_phi    = (const float*)d_in[4];
  const float* w_g      = (const float*)d_in[5];
  const float* b_g      = (const float*)d_in[6];
  const float* w_out    = (const float*)d_in[7];
  const float* b_out    = (const float*)d_in[8];
  const float* bn_gamma = (const float*)d_in[9];
  const float* bn_beta  = (const float*)d_in[10];
  float* out = (float*)d_out;

  u16* theta_t = (u16*)d_ws;                       // 2 MB
  u16* phi_t   = theta_t + (size_t)4 * NN * 64;    // 2 MB
  u16* gbuf    = phi_t   + (size_t)4 * NN * 64;    // 2 MB
  char* after  = (char*)(gbuf + (size_t)4 * NN * 64);
  const size_t used = (size_t)(after - (char*)d_ws);
  const size_t perS = (size_t)4 * NN * 64 * 2 + (size_t)4 * NN * 4; // ~2.16 MB

  int S = 1;
  if      (ws_size >= used + 8 * perS) S = 8;
  else if (ws_size >= used + 4 * perS) S = 4;
  else if (ws_size >= used + 2 * perS) S = 2;
  u16*   y_part = (u16*)after;
  float* l_part = (float*)(y_part + (size_t)S * 4 * NN * 64);

  proj_kernel<<<256, 512, 0, stream>>>(x, w_theta, b_theta, w_phi, b_phi,
                                       w_g, b_g, theta_t, phi_t, gbuf);
  if (S == 8)
    attn_kernel<8><<<256, 512, 0, stream>>>(theta_t, phi_t, gbuf, y_part, l_part);
  else if (S == 4)
    attn_kernel<16><<<128, 512, 0, stream>>>(theta_t, phi_t, gbuf, y_part, l_part);
  else if (S == 2)
    attn_kernel<32><<<64, 512, 0, stream>>>(theta_t, phi_t, gbuf, y_part, l_part);
  else
    attn_kernel<64><<<32, 512, 0, stream>>>(theta_t, phi_t, gbuf, y_part, l_part);
  combine_kernel<<<512, 256, 0, stream>>>(y_part, l_part, x, w_out, b_out,
                                          bn_gamma, bn_beta, out, S);
}

// Round 18
// 41.946 us; speedup vs baseline: 7.3510x; 1.1327x over previous
//
#include <hip/hip_runtime.h>

typedef __attribute__((ext_vector_type(4))) float f32x4;
typedef __attribute__((ext_vector_type(16))) float f32x16;
typedef __attribute__((ext_vector_type(8))) short bf16x8;
typedef unsigned short u16;
typedef unsigned int u32;

constexpr int NN = 4096;   // H*W

__device__ __forceinline__ u16 f2bf(float f){
  u32 u = __builtin_bit_cast(u32, f);
  u += 0x7FFFu + ((u >> 16) & 1u);          // round-to-nearest-even
  return (u16)(u >> 16);
}
__device__ __forceinline__ u32 cvtpk(float lo, float hi){
  u32 r;
  asm("v_cvt_pk_bf16_f32 %0, %1, %2" : "=v"(r) : "v"(lo), "v"(hi));
  return r;
}
__device__ __forceinline__ float fexp2(float x){
  float r;
  asm("v_exp_f32 %0, %1" : "=v"(r) : "v"(x));
  return r;
}
__device__ __forceinline__ void async16(void* lds, const void* g){
  __builtin_amdgcn_global_load_lds((const __attribute__((address_space(1))) void*)g,
                                   (__attribute__((address_space(3))) void*)lds,
                                   16, 0, 0);
}

// ---------------------------------------------------------------------------
// proj v9 (MFMA): [4096n x 64c] @ [64c x 192o] on matrix cores.
// 256 blocks = (b, 64-n chunk), 512 thr. LDS: x bf16 [n][c] swizzled (8KB)
// + W bf16 [o_glob][c] swizzled (24KB) + bias (768B). 12 tiles 32o x 32n,
// 4 mfma_32x32x16 each; fragment/D layouts identical to validated attn usage.
// theta gets *log2e folded. theta_t/phi_t: [b][n][o]; g: [b][o][n].
// ---------------------------------------------------------------------------
__global__ __launch_bounds__(512) void proj_kernel(
    const float* __restrict__ x,
    const float* __restrict__ wth, const float* __restrict__ bth,
    const float* __restrict__ wph, const float* __restrict__ bph,
    const float* __restrict__ wg,  const float* __restrict__ bg,
    u16* __restrict__ theta_t, u16* __restrict__ phi_t, u16* __restrict__ gbuf)
{
  __shared__ u16 W_lds[192 * 64];   // [o_glob][c], rows 128B, XOR-swizzled
  __shared__ u16 x_lds[64 * 64];    // [n_loc][c], rows 128B, XOR-swizzled
  __shared__ float Bsm[192];

  const int t  = threadIdx.x;
  const int b  = blockIdx.x >> 6;
  const int nc = blockIdx.x & 63;   // 64-n chunk

  // ---- stage W (3 x 64x64 f32 -> bf16, swizzled) ----
#pragma unroll
  for (int i = 0; i < 6; ++i){
    const int idx4 = i * 512 + t;            // float4 index 0..3071
    const float4 v = (idx4 < 1024) ? ((const float4*)wth)[idx4]
                   : (idx4 < 2048) ? ((const float4*)wph)[idx4 - 1024]
                                   : ((const float4*)wg)[idx4 - 2048];
    const int row = idx4 >> 4;               // o_glob 0..191 (16 float4/row)
    const int b0  = row * 128 + (idx4 & 15) * 8;   // byte offset, 8B-aligned
    const int adr = ((b0 & ~15) ^ ((row & 7) << 4)) + (b0 & 15);
    uint2 pk;
    pk.x = cvtpk(v.x, v.y); pk.y = cvtpk(v.z, v.w);
    *(uint2*)((char*)W_lds + adr) = pk;
  }
  if (t < 192) Bsm[t] = (t < 64) ? bth[t] : (t < 128) ? bph[t - 64] : bg[t - 128];

  // ---- stage x tile (64c x 64n f32 -> bf16, transposed to [n][c]) ----
#pragma unroll
  for (int i = 0; i < 2; ++i){
    const int idx4 = i * 512 + t;            // 0..1023 (16 float4 per c-row)
    const int c    = idx4 >> 4;
    const int n4   = idx4 & 15;              // n-group
    const float4 v = *(const float4*)&x[((size_t)(b * 64 + c)) * NN + nc * 64 + n4 * 4];
    const float vv[4] = {v.x, v.y, v.z, v.w};
#pragma unroll
    for (int jj = 0; jj < 4; ++jj){
      const int n  = n4 * 4 + jj;
      const int b0 = n * 128 + c * 2;
      const int adr = ((b0 & ~15) ^ ((n & 7) << 4)) + (b0 & 15);
      *(u16*)((char*)x_lds + adr) = f2bf(vv[jj]);
    }
  }
  __syncthreads();

  const int w  = __builtin_amdgcn_readfirstlane(t >> 6);  // 0..7
  const int l  = t & 63;
  const int cc = l & 31;
  const int h  = l >> 5;
  const int sw = (cc & 7) << 4;

  // wave w handles tiles {w, w+8 (if w<4)} of 12 = (o-tile 0..5) x (n-sub 0..1)
#pragma unroll
  for (int rep = 0; rep < 2; ++rep){
    const int tile = w + rep * 8;
    if (tile >= 12) break;
    const int ot   = tile >> 1;              // o-tile 0..5
    const int nsub = tile & 1;               // n-sub 0..1
    const int mat  = ot >> 1;                // 0 theta, 1 phi, 2 g

    f32x16 acc;
#pragma unroll
    for (int i = 0; i < 16; ++i) acc[i] = 0.f;
#pragma unroll
    for (int ks = 0; ks < 4; ++ks){
      const int ko = (ks * 32 + h * 16) ^ sw;
      const bf16x8 af = *(const bf16x8*)((const char*)W_lds + (ot * 32 + cc) * 128 + ko);
      const bf16x8 bf = *(const bf16x8*)((const char*)x_lds + (nsub * 32 + cc) * 128 + ko);
      acc = __builtin_amdgcn_mfma_f32_32x32x16_bf16(af, bf, acc, 0, 0, 0);
    }

    const int n = nc * 64 + nsub * 32 + cc;  // this lane's output n
    if (mat < 2){
      u16* base = (mat == 0) ? theta_t : phi_t;
      u16* dst  = base + ((size_t)(b * NN + n)) * 64;
#pragma unroll
      for (int q2 = 0; q2 < 4; ++q2){
        const int ob = (ot & 1) * 32 + q2 * 8 + 4 * h;   // 4 consecutive o
        float v0 = acc[q2 * 4 + 0] + Bsm[mat * 64 + ob + 0];
        float v1 = acc[q2 * 4 + 1] + Bsm[mat * 64 + ob + 1];
        float v2 = acc[q2 * 4 + 2] + Bsm[mat * 64 + ob + 2];
        float v3 = acc[q2 * 4 + 3] + Bsm[mat * 64 + ob + 3];
        if (mat == 0){
          v0 *= 1.44269504088896340736f; v1 *= 1.44269504088896340736f;
          v2 *= 1.44269504088896340736f; v3 *= 1.44269504088896340736f;
        }
        uint2 pk; pk.x = cvtpk(v0, v1); pk.y = cvtpk(v2, v3);
        *(uint2*)(dst + ob) = pk;
      }
    } else {
#pragma unroll
      for (int r = 0; r < 16; ++r){
        const int o = (ot & 1) * 32 + (r & 3) + 8 * (r >> 2) + 4 * h;
        gbuf[((size_t)(b * 64 + o)) * NN + n] = f2bf(acc[r] + Bsm[128 + o]);
      }
    }
  }
}

// ---------------------------------------------------------------------------
// attn (R17 validated, unchanged): BM=512 — 2 n-tiles per wave. 3-buffer
// counted-vmcnt schedule (2 loads/stage/wave quantum; pair-staging BANNED).
// grid = 32*S, 512 threads.
// ---------------------------------------------------------------------------
template<int TPB>
__global__ __launch_bounds__(512, 2) void attn_kernel(
    const u16* __restrict__ theta_t, const u16* __restrict__ phi_t,
    const u16* __restrict__ gbuf,
    u16* __restrict__ y_part, float* __restrict__ l_part)
{
  __shared__ u16 phi_sm[3][64 * 64];  // [buf][m_loc*64+o], XOR-swizzled
  __shared__ u16 g_sm[3][64 * 64];    // [buf][o*64+m_loc], XOR-swizzled

  const int j   = blockIdx.x;
  const int cpx = gridDim.x >> 3;
  const int lb  = (j & 7) * cpx + (j >> 3);   // bijective (grid % 8 == 0)

  const int ms  = lb >> 5;            // m-split index
  const int pr  = lb & 31;            // batch*8 + n-chunk
  const int b   = pr >> 3;
  const int n0  = (pr & 7) * 512;

  const int tid = threadIdx.x;
  const int w   = __builtin_amdgcn_readfirstlane(tid >> 6); // 0..7
  const int l   = tid & 63;
  const int cc  = l & 31;
  const int h   = l >> 5;
  const int sw  = (cc & 7) << 4;
  const int rb  = cc * 128;

  const u16* thb = theta_t + (size_t)b * NN * 64;

  bf16x8 tf0[4], tf1[4];
#pragma unroll
  for (int ks = 0; ks < 4; ++ks){
    tf0[ks] = *(const bf16x8*)(thb + (size_t)(n0 + w * 64 + cc) * 64 + ks * 16 + h * 8);
    tf1[ks] = *(const bf16x8*)(thb + (size_t)(n0 + w * 64 + 32 + cc) * 64 + ks * 16 + h * 8);
  }

  const int m0 = ms * TPB;
  const int r8 = l >> 3;
  const int c8 = l & 7;
  const u16* phi_src = phi_t + (size_t)b * NN * 64
                     + (size_t)(m0 * 64 + w * 8 + r8) * 64 + (c8 ^ r8) * 8;
  const u16* g_src   = gbuf + (size_t)b * 64 * NN
                     + (size_t)(w * 8 + r8) * NN + m0 * 64 + (c8 ^ r8) * 8;

  f32x16 yacc00, yacc01, yacc10, yacc11;   // [nt][o-half]
#pragma unroll
  for (int i = 0; i < 16; ++i){
    yacc00[i] = 0.f; yacc01[i] = 0.f; yacc10[i] = 0.f; yacc11[i] = 0.f;
  }
  float lacc0 = 0.f, lacc1 = 0.f;

  async16(&phi_sm[0][w * 512], phi_src);
  async16(&g_sm[0][w * 512],   g_src);
  phi_src += 4096; g_src += 64;
  async16(&phi_sm[1][w * 512], phi_src);
  async16(&g_sm[1][w * 512],   g_src);
  phi_src += 4096; g_src += 64;

#pragma unroll
  for (int it = 0; it < TPB; ++it){
    const int cur = it % 3;
    if (it < TPB - 1)
      asm volatile("s_waitcnt vmcnt(2)" ::: "memory");
    else
      asm volatile("s_waitcnt vmcnt(0)" ::: "memory");
    asm volatile("" ::: "memory");
    __builtin_amdgcn_s_barrier();
    asm volatile("" ::: "memory");
    if (it + 2 < TPB){
      async16(&phi_sm[(it + 2) % 3][w * 512], phi_src);
      async16(&g_sm[(it + 2) % 3][w * 512],   g_src);
      phi_src += 4096; g_src += 64;
    }

    const char* phiB = (const char*)&phi_sm[cur][0];
    const char* gB   = (const char*)&g_sm[cur][0];

#pragma unroll
    for (int tt = 0; tt < 2; ++tt){
      __builtin_amdgcn_s_setprio(1);
      f32x16 p0, p1;
#pragma unroll
      for (int i = 0; i < 16; ++i){ p0[i] = 0.f; p1[i] = 0.f; }
#pragma unroll
      for (int ks = 0; ks < 4; ++ks){
        const bf16x8 pf = *(const bf16x8*)(phiB + tt * 4096 + rb + ((ks * 32 + h * 16) ^ sw));
        p0 = __builtin_amdgcn_mfma_f32_32x32x16_bf16(pf, tf0[ks], p0, 0, 0, 0);
        p1 = __builtin_amdgcn_mfma_f32_32x32x16_bf16(pf, tf1[ks], p1, 0, 0, 0);
      }
      __builtin_amdgcn_s_setprio(0);

      u32 wpk0[4][2], wpk1[4][2];
#pragma unroll
      for (int rq = 0; rq < 4; ++rq){
        float e0 = fexp2(p0[4 * rq + 0]), e1 = fexp2(p0[4 * rq + 1]);
        float e2 = fexp2(p0[4 * rq + 2]), e3 = fexp2(p0[4 * rq + 3]);
        lacc0 += (e0 + e1) + (e2 + e3);
        wpk0[rq][0] = cvtpk(e0, e1);
        wpk0[rq][1] = cvtpk(e2, e3);
        e0 = fexp2(p1[4 * rq + 0]); e1 = fexp2(p1[4 * rq + 1]);
        e2 = fexp2(p1[4 * rq + 2]); e3 = fexp2(p1[4 * rq + 3]);
        lacc1 += (e0 + e1) + (e2 + e3);
        wpk1[rq][0] = cvtpk(e0, e1);
        wpk1[rq][1] = cvtpk(e2, e3);
      }

      __builtin_amdgcn_s_setprio(1);
#pragma unroll
      for (int par = 0; par < 2; ++par){
        u32 A0 = wpk0[2 * par][0],     A1 = wpk0[2 * par][1];
        u32 B0 = wpk0[2 * par + 1][0], B1 = wpk0[2 * par + 1][1];
        asm("v_permlane32_swap_b32 %0, %1" : "+v"(A0), "+v"(B0));
        asm("v_permlane32_swap_b32 %0, %1" : "+v"(A1), "+v"(B1));
        union { u32 u[4]; bf16x8 v; } pw0;
        pw0.u[0] = A0; pw0.u[1] = A1; pw0.u[2] = B0; pw0.u[3] = B1;
        u32 C0 = wpk1[2 * par][0],     C1 = wpk1[2 * par][1];
        u32 D0 = wpk1[2 * par + 1][0], D1 = wpk1[2 * par + 1][1];
        asm("v_permlane32_swap_b32 %0, %1" : "+v"(C0), "+v"(D0));
        asm("v_permlane32_swap_b32 %0, %1" : "+v"(C1), "+v"(D1));
        union { u32 u[4]; bf16x8 v; } pw1;
        pw1.u[0] = C0; pw1.u[1] = C1; pw1.u[2] = D0; pw1.u[3] = D1;

        const int s   = tt * 2 + par;
        const int gof = (s * 32 + h * 16) ^ sw;
        const bf16x8 g0 = *(const bf16x8*)(gB + rb + gof);
        const bf16x8 g1 = *(const bf16x8*)(gB + 4096 + rb + gof);
        yacc00 = __builtin_amdgcn_mfma_f32_32x32x16_bf16(pw0.v, g0, yacc00, 0, 0, 0);
        yacc01 = __builtin_amdgcn_mfma_f32_32x32x16_bf16(pw0.v, g1, yacc01, 0, 0, 0);
        yacc10 = __builtin_amdgcn_mfma_f32_32x32x16_bf16(pw1.v, g0, yacc10, 0, 0, 0);
        yacc11 = __builtin_amdgcn_mfma_f32_32x32x16_bf16(pw1.v, g1, yacc11, 0, 0, 0);
      }
      __builtin_amdgcn_s_setprio(0);
    }
  }

  {
    u32 la = __builtin_bit_cast(u32, lacc0), lb2 = la;
    asm("v_permlane32_swap_b32 %0, %1" : "+v"(la), "+v"(lb2));
    const float lt0 = __builtin_bit_cast(float, la) + __builtin_bit_cast(float, lb2);
    u32 lc = __builtin_bit_cast(u32, lacc1), ld = lc;
    asm("v_permlane32_swap_b32 %0, %1" : "+v"(lc), "+v"(ld));
    const float lt1 = __builtin_bit_cast(float, lc) + __builtin_bit_cast(float, ld);
    if (l < 32){
      l_part[(size_t)(ms * 4 + b) * NN + n0 + w * 64 + cc]      = lt0;
      l_part[(size_t)(ms * 4 + b) * NN + n0 + w * 64 + 32 + cc] = lt1;
    }
  }

  u16* yp0 = y_part + ((size_t)(ms * 4 + b) * NN + n0 + w * 64) * 64 + cc;
  u16* yp1 = y_part + ((size_t)(ms * 4 + b) * NN + n0 + w * 64 + 32) * 64 + cc;
#pragma unroll
  for (int r = 0; r < 16; ++r){
    const int nl = (r & 3) + 8 * (r >> 2) + 4 * h;
    yp0[(size_t)nl * 64]      = f2bf(yacc00[r]);
    yp0[(size_t)nl * 64 + 32] = f2bf(yacc01[r]);
    yp1[(size_t)nl * 64]      = f2bf(yacc10[r]);
    yp1[(size_t)nl * 64 + 32] = f2bf(yacc11[r]);
  }
}

// ---------------------------------------------------------------------------
// combine (validated): 512 blocks x 32 rows. Sum S bf16 partials, normalize,
// w_out GEMM + bias/ReLU/BN + residual.
// ---------------------------------------------------------------------------
__global__ __launch_bounds__(256) void combine_kernel(
    const u16* __restrict__ y_part, const float* __restrict__ l_part,
    const float* __restrict__ x,
    const float* __restrict__ w_out, const float* __restrict__ b_out,
    const float* __restrict__ bn_gamma, const float* __restrict__ bn_beta,
    float* __restrict__ out, int S)
{
  __shared__ u16 y_sm[32 * 64];       // [row][o] bf16, swizzled
  __shared__ float inv_sm[32];

  const int cb   = blockIdx.x;            // 0..511
  const int b    = cb >> 7;
  const int nin  = (cb & 127) * 32;       // row base within batch
  const int t    = threadIdx.x;
  const int row  = t >> 3;                // 0..31
  const int ch   = t & 7;                 // 16B chunk (8 bf16)

  float s[8] = {0.f,0.f,0.f,0.f,0.f,0.f,0.f,0.f};
  for (int ms = 0; ms < S; ++ms){
    const u16* src = y_part + ((size_t)(ms * 4 + b) * NN + nin + row) * 64 + ch * 8;
    const uint4 v = *(const uint4*)src;
    const u32 ww[4] = {v.x, v.y, v.z, v.w};
#pragma unroll
    for (int i = 0; i < 4; ++i){
      s[2 * i]     += __builtin_bit_cast(float, ww[i] << 16);
      s[2 * i + 1] += __builtin_bit_cast(float, ww[i] & 0xFFFF0000u);
    }
  }
  if (t < 32){
    float ls = 0.f;
    for (int ms = 0; ms < S; ++ms)
      ls += l_part[(size_t)(ms * 4 + b) * NN + nin + t];
    inv_sm[t] = 1.0f / ls;
  }
  __syncthreads();

  {
    const float inv = inv_sm[row];
    uint4 pk;
    pk.x = cvtpk(s[0] * inv, s[1] * inv);
    pk.y = cvtpk(s[2] * inv, s[3] * inv);
    pk.z = cvtpk(s[4] * inv, s[5] * inv);
    pk.w = cvtpk(s[6] * inv, s[7] * inv);
    *(uint4*)((char*)y_sm + ((row * 128 + ch * 16) ^ ((row & 7) << 4))) = pk;
  }
  __syncthreads();

  const int w   = __builtin_amdgcn_readfirstlane(t >> 6);
  const int l   = t & 63;
  const int q   = l & 15;
  const int gg  = l >> 4;
  const int swz = (q & 7) << 4;

  bf16x8 wf[2];
#pragma unroll
  for (int ks = 0; ks < 2; ++ks){
    bf16x8 v;
#pragma unroll
    for (int jj = 0; jj < 8; ++jj)
      v[jj] = (short)f2bf(w_out[(w * 16 + q) * 64 + ks * 32 + gg * 8 + jj]);
    wf[ks] = v;
  }
  f32x4 zacc[2];
  zacc[0] = (f32x4){0.f, 0.f, 0.f, 0.f};
  zacc[1] = (f32x4){0.f, 0.f, 0.f, 0.f};
#pragma unroll
  for (int ks = 0; ks < 2; ++ks)
#pragma unroll
    for (int ns = 0; ns < 2; ++ns){
      const int off = (((ns * 16 + q) * 128) + ks * 64 + gg * 16) ^ swz;
      const bf16x8 yf = *(const bf16x8*)((const char*)y_sm + off);
      zacc[ns] = __builtin_amdgcn_mfma_f32_16x16x32_bf16(wf[ks], yf, zacc[ns], 0, 0, 0);
    }

  float bo[4], sc_[4], bb_[4];
#pragma unroll
  for (int r = 0; r < 4; ++r){
    const int c = w * 16 + gg * 4 + r;
    bo[r]  = b_out[c];
    sc_[r] = bn_gamma[c] * 0.99999500003749969f;  // 1/sqrt(1+1e-5)
    bb_[r] = bn_beta[c];
  }
#pragma unroll
  for (int ns = 0; ns < 2; ++ns)
#pragma unroll
    for (int r = 0; r < 4; ++r){
      const int c  = w * 16 + gg * 4 + r;
      const int ng = nin + ns * 16 + q;
      const size_t idx = ((size_t)(b * 64 + c)) * NN + ng;
      float z = zacc[ns][r] + bo[r];
      z = fmaxf(z, 0.0f);
      z = z * sc_[r] + bb_[r];
      out[idx] = x[idx] + z;
    }
}

// ---------------------------------------------------------------------------
extern "C" void kernel_launch(void* const* d_in, const int* in_sizes, int n_in,
                              void* d_out, int out_size, void* d_ws, size_t ws_size,
                              hipStream_t stream)
{
  (void)in_sizes; (void)n_in; (void)out_size;
  const float* x        = (const float*)d_in[0];
  const float* w_theta  = (const float*)d_in[1];
  const float* b_theta  = (const float*)d_in[2];
  const float* w_phi    = (const float*)d_in[3];
  const float* b_phi    = (const float*)d_in[4];
  const float* w_g      = (const float*)d_in[5];
  const float* b_g      = (const float*)d_in[6];
  const float* w_out    = (const float*)d_in[7];
  const float* b_out    = (const float*)d_in[8];
  const float* bn_gamma = (const float*)d_in[9];
  const float* bn_beta  = (const float*)d_in[10];
  float* out = (float*)d_out;

  u16* theta_t = (u16*)d_ws;                       // 2 MB
  u16* phi_t   = theta_t + (size_t)4 * NN * 64;    // 2 MB
  u16* gbuf    = phi_t   + (size_t)4 * NN * 64;    // 2 MB
  char* after  = (char*)(gbuf + (size_t)4 * NN * 64);
  const size_t used = (size_t)(after - (char*)d_ws);
  const size_t perS = (size_t)4 * NN * 64 * 2 + (size_t)4 * NN * 4; // ~2.16 MB

  int S = 1;
  if      (ws_size >= used + 8 * perS) S = 8;
  else if (ws_size >= used + 4 * perS) S = 4;
  else if (ws_size >= used + 2 * perS) S = 2;
  u16*   y_part = (u16*)after;
  float* l_part = (float*)(y_part + (size_t)S * 4 * NN * 64);

  proj_kernel<<<256, 512, 0, stream>>>(x, w_theta, b_theta, w_phi, b_phi,
                                       w_g, b_g, theta_t, phi_t, gbuf);
  if (S == 8)
    attn_kernel<8><<<256, 512, 0, stream>>>(theta_t, phi_t, gbuf, y_part, l_part);
  else if (S == 4)
    attn_kernel<16><<<128, 512, 0, stream>>>(theta_t, phi_t, gbuf, y_part, l_part);
  else if (S == 2)
    attn_kernel<32><<<64, 512, 0, stream>>>(theta_t, phi_t, gbuf, y_part, l_part);
  else
    attn_kernel<64><<<32, 512, 0, stream>>>(theta_t, phi_t, gbuf, y_part, l_part);
  combine_kernel<<<512, 256, 0, stream>>>(y_part, l_part, x, w_out, b_out,
                                          bn_gamma, bn_beta, out, S);
}